// Round 1
// baseline (2209.526 us; speedup 1.0000x reference)
//
#include <hip/hip_runtime.h>

static constexpr int NB = 2048;

// rotated-3x3 tap permutation: position dst[r][k] of rotated kernel r receives w tap k
static constexpr int DST[8][9] = {
  {8,7,6,5,4,3,2,1,0},
  {5,8,7,2,4,6,1,0,3},
  {2,5,8,1,4,7,0,3,6},
  {1,2,5,0,4,8,3,6,7},
  {0,1,2,3,4,5,6,7,8},
  {3,0,1,6,4,2,7,8,5},
  {6,3,0,7,4,1,8,5,2},
  {7,6,3,8,4,0,5,2,1},
};

static constexpr int S1  = 2048*16*784;   // 25,690,112 floats
static constexpr int SP2 = 2048*16*196;   //  6,422,528

// ---------------- zero stats region ----------------
__global__ __launch_bounds__(256) void k_zero(float* st){
  int i = blockIdx.x*256 + threadIdx.x;
  if (i < 2048) st[i] = 0.f;
}

// ---------------- conv1: 1->16ch rotated, separate ----------------
__global__ __launch_bounds__(256) void k_conv1(const float* __restrict__ x,
                                               const float* __restrict__ w1,
                                               float* __restrict__ y1){
  int idx = blockIdx.x*256 + threadIdx.x;       // NB*784 exact
  int b = idx / 784, pix = idx - b*784;
  int py = pix / 28, px = pix - py*28;
  const float* xb = x + (size_t)b*784;
  float tap[9];
  #pragma unroll
  for (int d=0; d<9; d++){
    int dy = d/3 - 1, dx = d%3 - 1;
    int yy = py + dy, xx = px + dx;
    float v = 0.f;
    if (yy>=0 && yy<28 && xx>=0 && xx<28) v = xb[yy*28+xx];
    tap[d] = v;
  }
  float w[18];
  #pragma unroll
  for (int i=0;i<18;i++) w[i] = w1[i];
  float* yb = y1 + (size_t)b*12544 + pix;
  #pragma unroll
  for (int rot=0; rot<8; rot++){
    #pragma unroll
    for (int u=0; u<2; u++){
      float acc = 0.f;
      #pragma unroll
      for (int k=0;k<9;k++) acc += w[u*9+k]*tap[DST[rot][k]];
      yb[(rot*2+u)*784] = acc;
    }
  }
}

// ---------------- per-channel sum/sumsq ----------------
template<int C, int HW>
__global__ __launch_bounds__(256) void k_stats(const float* __restrict__ y, float* __restrict__ st){
  int c = blockIdx.y;
  const int N = NB*HW;
  float s=0.f, s2=0.f;
  for (int i = blockIdx.x*256 + threadIdx.x; i < N; i += gridDim.x*256){
    int b = i / HW, hw = i - b*HW;
    float v = y[((size_t)b*C + c)*HW + hw];
    s += v; s2 += v*v;
  }
  #pragma unroll
  for (int off=32; off; off>>=1){ s += __shfl_down(s, off); s2 += __shfl_down(s2, off); }
  __shared__ float sh[8];
  if ((threadIdx.x & 63) == 0){ sh[(threadIdx.x>>6)*2] = s; sh[(threadIdx.x>>6)*2+1] = s2; }
  __syncthreads();
  if (threadIdx.x == 0){
    atomicAdd(&st[c],    sh[0]+sh[2]+sh[4]+sh[6]);
    atomicAdd(&st[64+c], sh[1]+sh[3]+sh[5]+sh[7]);
  }
}

// ---------------- BN finalize: a = g*rsqrt(var+eps), b = beta - mu*a ----------------
__global__ void k_fin(const float* __restrict__ st, const float* __restrict__ g,
                      const float* __restrict__ be, float* __restrict__ coef,
                      int C, int gmask, float invN){
  int c = threadIdx.x;
  if (c >= C) return;
  float mu  = st[c]*invN;
  float var = st[64+c]*invN - mu*mu;
  float a = g[c & gmask] * rsqrtf(var + 1e-5f);
  coef[c]    = a;
  coef[64+c] = be[c & gmask] - mu*a;
}

// ---------------- conv2: 16->16 rotated non-separate, fused bn1+relu on read ----------------
__global__ __launch_bounds__(256) void k_conv2(const float* __restrict__ y1,
                                               const float* __restrict__ w2,
                                               const float* __restrict__ coef,
                                               float* __restrict__ y2){
  __shared__ float ws[288];
  __shared__ float ca[16], cb[16];
  for (int i=threadIdx.x; i<288; i+=256) ws[i] = w2[i];
  if (threadIdx.x < 16){ ca[threadIdx.x] = coef[threadIdx.x]; cb[threadIdx.x] = coef[64+threadIdx.x]; }
  __syncthreads();
  int idx = blockIdx.x*256 + threadIdx.x;       // NB*784 exact
  int b = idx / 784, pix = idx - b*784;
  int py = pix / 28, px = pix - py*28;
  const float* yb = y1 + (size_t)b*12544;
  float acc[16];
  #pragma unroll
  for (int i=0;i<16;i++) acc[i] = 0.f;
  #pragma unroll
  for (int half=0; half<2; half++){
    float tap[8][9];
    #pragma unroll
    for (int tl=0; tl<8; tl++){
      int ci = half*8 + tl;
      float a = ca[ci], bo = cb[ci];
      const float* src = yb + ci*784;
      #pragma unroll
      for (int d=0; d<9; d++){
        int dy = d/3 - 1, dx = d%3 - 1;
        int yy = py + dy, xx = px + dx;
        float v = 0.f;
        if (yy>=0 && yy<28 && xx>=0 && xx<28) v = fmaxf(src[yy*28+xx]*a + bo, 0.f);
        tap[tl][d] = v;
      }
    }
    #pragma unroll
    for (int wc=0; wc<16; wc++){
      #pragma unroll
      for (int u=0; u<2; u++){
        float wv[9];
        #pragma unroll
        for (int k=0;k<9;k++) wv[k] = ws[(u*16+wc)*9 + k];
        #pragma unroll
        for (int rot=0; rot<8; rot++){
          int bblk = ((wc>>1) + rot) & 7;
          if ((bblk>>2) != half) continue;      // compile-time filtered
          int tl = (bblk&3)*2 + (wc&1);
          float s = 0.f;
          #pragma unroll
          for (int k=0;k<9;k++) s += wv[k]*tap[tl][DST[rot][k]];
          acc[rot*2+u] += s;
        }
      }
    }
  }
  float* ob = y2 + (size_t)b*12544 + pix;
  #pragma unroll
  for (int c=0;c<16;c++) ob[c*784] = acc[c];
}

// ---------------- bn+relu+2x2 maxpool ----------------
template<int C, int HI>
__global__ __launch_bounds__(256) void k_pool(const float* __restrict__ y,
                                              const float* __restrict__ coef,
                                              float* __restrict__ p){
  constexpr int HO = HI/2;
  int idx = blockIdx.x*256 + threadIdx.x;       // exact
  int xo = idx % HO; int t1 = idx / HO;
  int yo = t1 % HO; int t2 = t1 / HO;
  int c = t2 % C;   int b = t2 / C;
  float a = coef[c], bo = coef[64+c];
  const float* src = y + ((size_t)b*C + c)*(HI*HI) + yo*2*HI + xo*2;
  float m = fmaxf(fmaxf(src[0]*a+bo, src[1]*a+bo), fmaxf(src[HI]*a+bo, src[HI+1]*a+bo));
  p[idx] = fmaxf(m, 0.f);
}

// ---------------- conv3: 16->32 rotated non-separate (input already normalized) ----------------
__global__ __launch_bounds__(256) void k_conv3(const float* __restrict__ p2,
                                               const float* __restrict__ w3,
                                               float* __restrict__ y3){
  __shared__ float ws[576];
  for (int i=threadIdx.x; i<576; i+=256) ws[i] = w3[i];
  __syncthreads();
  int idx = blockIdx.x*256 + threadIdx.x;       // NB*196 exact
  int b = idx / 196, pix = idx - b*196;
  int py = pix / 14, px = pix - py*14;
  const float* yb = p2 + (size_t)b*3136;
  float acc[32];
  #pragma unroll
  for (int i=0;i<32;i++) acc[i] = 0.f;
  #pragma unroll
  for (int half=0; half<2; half++){
    float tap[8][9];
    #pragma unroll
    for (int tl=0; tl<8; tl++){
      int ci = half*8 + tl;
      const float* src = yb + ci*196;
      #pragma unroll
      for (int d=0; d<9; d++){
        int dy = d/3 - 1, dx = d%3 - 1;
        int yy = py + dy, xx = px + dx;
        float v = 0.f;
        if (yy>=0 && yy<14 && xx>=0 && xx<14) v = src[yy*14+xx];
        tap[tl][d] = v;
      }
    }
    #pragma unroll
    for (int wc=0; wc<16; wc++){
      #pragma unroll
      for (int u=0; u<4; u++){
        float wv[9];
        #pragma unroll
        for (int k=0;k<9;k++) wv[k] = ws[(u*16+wc)*9 + k];
        #pragma unroll
        for (int rot=0; rot<8; rot++){
          int bblk = ((wc>>1) + rot) & 7;
          if ((bblk>>2) != half) continue;
          int tl = (bblk&3)*2 + (wc&1);
          float s = 0.f;
          #pragma unroll
          for (int k=0;k<9;k++) s += wv[k]*tap[tl][DST[rot][k]];
          acc[rot*4+u] += s;
        }
      }
    }
  }
  float* ob = y3 + (size_t)b*6272 + pix;
  #pragma unroll
  for (int c=0;c<32;c++) ob[c*196] = acc[c];
}

// ---------------- nms: sum of bn3+relu values != rotation-group max ----------------
__global__ __launch_bounds__(256) void k_nms(const float* __restrict__ y3,
                                             const float* __restrict__ coef,
                                             float* __restrict__ accum){
  int idx = blockIdx.x*256 + threadIdx.x;       // NB*4*196 exact
  int hw = idx % 196; int t1 = idx / 196;
  int c4 = t1 & 3;    int b = t1 >> 2;
  const float* base = y3 + ((size_t)b*32 + c4*8)*196 + hw;
  float v[8]; float vmax = -1e30f;
  #pragma unroll
  for (int r=0;r<8;r++){
    int c = c4*8 + r;
    float z = fmaxf(base[r*196]*coef[c] + coef[64+c], 0.f);
    v[r] = z;
    vmax = fmaxf(vmax, z);
  }
  float local = 0.f;
  #pragma unroll
  for (int r=0;r<8;r++) local += (v[r] != vmax) ? v[r] : 0.f;
  #pragma unroll
  for (int off=32; off; off>>=1) local += __shfl_down(local, off);
  __shared__ float sh[4];
  if ((threadIdx.x & 63) == 0) sh[threadIdx.x>>6] = local;
  __syncthreads();
  if (threadIdx.x == 0) atomicAdd(accum, sh[0]+sh[1]+sh[2]+sh[3]);
}

// ---------------- conv4: 32->32 standard, fused bn3+relu; 2x2 pixel tile, 16-oc half ----------------
__global__ __launch_bounds__(256) void k_conv4(const float* __restrict__ y3,
                                               const float* __restrict__ w4,
                                               const float* __restrict__ coef,
                                               float* __restrict__ y4){
  __shared__ float ws[4608];
  __shared__ float ca[32], cb[32];
  int ohalf = blockIdx.x / 392;
  int inner = blockIdx.x - ohalf*392;
  for (int i=threadIdx.x; i<4608; i+=256) ws[i] = w4[ohalf*4608 + i];
  if (threadIdx.x < 32){ ca[threadIdx.x] = coef[threadIdx.x]; cb[threadIdx.x] = coef[64+threadIdx.x]; }
  __syncthreads();
  int tg = inner*256 + threadIdx.x;
  int b = tg / 49, tile = tg - b*49;
  int ty = tile/7;
  int ty2 = ty*2, tx2 = (tile - ty*7)*2;
  const float* src = y3 + (size_t)b*6272;
  float acc[16][4];
  #pragma unroll
  for (int o=0;o<16;o++){ acc[o][0]=0.f; acc[o][1]=0.f; acc[o][2]=0.f; acc[o][3]=0.f; }
  for (int ci=0; ci<32; ci++){
    float a = ca[ci], bo = cb[ci];
    const float* s2 = src + ci*196;
    float t[16];
    #pragma unroll
    for (int r=0;r<4;r++){
      int iy = ty2 - 1 + r;
      bool vy = (iy>=0 && iy<14);
      #pragma unroll
      for (int c2=0;c2<4;c2++){
        int ix = tx2 - 1 + c2;
        float v = 0.f;
        if (vy && ix>=0 && ix<14) v = fmaxf(s2[iy*14+ix]*a + bo, 0.f);
        t[r*4+c2] = v;
      }
    }
    #pragma unroll
    for (int o=0;o<16;o++){
      const float* wr = &ws[(o*32+ci)*9];
      #pragma unroll
      for (int k=0;k<9;k++){
        float w = wr[k];
        int dy = k/3, dx = k - dy*3;
        acc[o][0] += w*t[dy*4+dx];
        acc[o][1] += w*t[dy*4+dx+1];
        acc[o][2] += w*t[(dy+1)*4+dx];
        acc[o][3] += w*t[(dy+1)*4+dx+1];
      }
    }
  }
  #pragma unroll
  for (int o=0;o<16;o++){
    float* dst = y4 + ((size_t)b*32 + ohalf*16 + o)*196;
    dst[ty2*14 + tx2]       = acc[o][0];
    dst[ty2*14 + tx2+1]     = acc[o][1];
    dst[(ty2+1)*14 + tx2]   = acc[o][2];
    dst[(ty2+1)*14 + tx2+1] = acc[o][3];
  }
}

// ---------------- conv5: 32->64 standard, raw input; 2x2 tile, 16-oc quarter ----------------
__global__ __launch_bounds__(256) void k_conv5(const float* __restrict__ p4,
                                               const float* __restrict__ w5,
                                               float* __restrict__ y5){
  __shared__ float ws[4608];
  int ohq = blockIdx.x >> 7;
  int inner = blockIdx.x & 127;
  for (int i=threadIdx.x; i<4608; i+=256) ws[i] = w5[ohq*4608 + i];
  __syncthreads();
  int tg = inner*256 + threadIdx.x;
  int b = tg >> 4, tile = tg & 15;
  int ty2 = (tile>>2)*2, tx2 = (tile&3)*2;
  const float* src = p4 + (size_t)b*1568;   // 32*49
  float acc[16][4];
  #pragma unroll
  for (int o=0;o<16;o++){ acc[o][0]=0.f; acc[o][1]=0.f; acc[o][2]=0.f; acc[o][3]=0.f; }
  for (int ci=0; ci<32; ci++){
    const float* s2 = src + ci*49;
    float t[16];
    #pragma unroll
    for (int r=0;r<4;r++){
      int iy = ty2 - 1 + r;
      bool vy = (iy>=0 && iy<7);
      #pragma unroll
      for (int c2=0;c2<4;c2++){
        int ix = tx2 - 1 + c2;
        float v = 0.f;
        if (vy && ix>=0 && ix<7) v = s2[iy*7+ix];
        t[r*4+c2] = v;
      }
    }
    #pragma unroll
    for (int o=0;o<16;o++){
      const float* wr = &ws[(o*32+ci)*9];
      #pragma unroll
      for (int k=0;k<9;k++){
        float w = wr[k];
        int dy = k/3, dx = k - dy*3;
        acc[o][0] += w*t[dy*4+dx];
        acc[o][1] += w*t[dy*4+dx+1];
        acc[o][2] += w*t[(dy+1)*4+dx];
        acc[o][3] += w*t[(dy+1)*4+dx+1];
      }
    }
  }
  #pragma unroll
  for (int o=0;o<16;o++){
    float* dst = y5 + ((size_t)b*64 + ohq*16 + o)*49;
    #pragma unroll
    for (int p=0;p<4;p++){
      int oy = ty2 + (p>>1), ox = tx2 + (p&1);
      if (oy<7 && ox<7) dst[oy*7+ox] = acc[o][p];
    }
  }
}

// ---------------- conv6: 64->64 standard, fused bn5+relu; 2x2 tile, 16-oc quarter ----------------
__global__ __launch_bounds__(256) void k_conv6(const float* __restrict__ y5,
                                               const float* __restrict__ w6,
                                               const float* __restrict__ coef,
                                               float* __restrict__ y6){
  __shared__ float ws[9216];
  __shared__ float ca[64], cb[64];
  int ohq = blockIdx.x >> 7;
  int inner = blockIdx.x & 127;
  for (int i=threadIdx.x; i<9216; i+=256) ws[i] = w6[ohq*9216 + i];
  if (threadIdx.x < 64){ ca[threadIdx.x] = coef[threadIdx.x]; cb[threadIdx.x] = coef[64+threadIdx.x]; }
  __syncthreads();
  int tg = inner*256 + threadIdx.x;
  int b = tg >> 4, tile = tg & 15;
  int ty2 = (tile>>2)*2, tx2 = (tile&3)*2;
  const float* src = y5 + (size_t)b*3136;   // 64*49
  float acc[16][4];
  #pragma unroll
  for (int o=0;o<16;o++){ acc[o][0]=0.f; acc[o][1]=0.f; acc[o][2]=0.f; acc[o][3]=0.f; }
  for (int ci=0; ci<64; ci++){
    float a = ca[ci], bo = cb[ci];
    const float* s2 = src + ci*49;
    float t[16];
    #pragma unroll
    for (int r=0;r<4;r++){
      int iy = ty2 - 1 + r;
      bool vy = (iy>=0 && iy<7);
      #pragma unroll
      for (int c2=0;c2<4;c2++){
        int ix = tx2 - 1 + c2;
        float v = 0.f;
        if (vy && ix>=0 && ix<7) v = fmaxf(s2[iy*7+ix]*a + bo, 0.f);
        t[r*4+c2] = v;
      }
    }
    #pragma unroll
    for (int o=0;o<16;o++){
      const float* wr = &ws[(o*64+ci)*9];
      #pragma unroll
      for (int k=0;k<9;k++){
        float w = wr[k];
        int dy = k/3, dx = k - dy*3;
        acc[o][0] += w*t[dy*4+dx];
        acc[o][1] += w*t[dy*4+dx+1];
        acc[o][2] += w*t[(dy+1)*4+dx];
        acc[o][3] += w*t[(dy+1)*4+dx+1];
      }
    }
  }
  #pragma unroll
  for (int o=0;o<16;o++){
    float* dst = y6 + ((size_t)b*64 + ohq*16 + o)*49;
    #pragma unroll
    for (int p=0;p<4;p++){
      int oy = ty2 + (p>>1), ox = tx2 + (p&1);
      if (oy<7 && ox<7) dst[oy*7+ox] = acc[o][p];
    }
  }
}

// ---------------- bn6+relu + 2x2 pool pad 1 (7 -> 4) ----------------
__global__ __launch_bounds__(256) void k_pool6(const float* __restrict__ y,
                                               const float* __restrict__ coef,
                                               float* __restrict__ p){
  int idx = blockIdx.x*256 + threadIdx.x;       // NB*64*16 exact
  int xo = idx & 3; int t1 = idx >> 2;
  int yo = t1 & 3;  int t2 = t1 >> 2;
  int c = t2 & 63;  int b = t2 >> 6;
  float a = coef[c], bo = coef[64+c];
  const float* src = y + ((size_t)b*64 + c)*49;
  float m = -1e30f;
  #pragma unroll
  for (int dy=0;dy<2;dy++){
    int iy = yo*2 - 1 + dy;
    if (iy < 0 || iy >= 7) continue;
    #pragma unroll
    for (int dx=0;dx<2;dx++){
      int ix = xo*2 - 1 + dx;
      if (ix < 0 || ix >= 7) continue;
      m = fmaxf(m, src[iy*7+ix]*a + bo);
    }
  }
  p[idx] = fmaxf(m, 0.f);
}

// ---------------- conv7 (pad 2, 4x4 kernel, 5x5 out) + bias + global max + nms write ----------------
__global__ __launch_bounds__(256) void k_conv7(const float* __restrict__ p6,
                                               const float* __restrict__ w7,
                                               const float* __restrict__ bias,
                                               const float* __restrict__ nmsa,
                                               float* __restrict__ out){
  __shared__ float ws[10240];
  __shared__ float xs[1024];
  __shared__ float vals[10][25];
  int b = blockIdx.x;
  for (int i=threadIdx.x; i<10240; i+=256) ws[i] = w7[i];
  for (int i=threadIdx.x; i<1024; i+=256) xs[i] = p6[(size_t)b*1024 + i];
  __syncthreads();
  int t = threadIdx.x;
  if (t < 250){
    int oc = t/25, pos = t - oc*25;
    int py = pos/5, px = pos - py*5;
    int ky0 = max(0, 2-py), ky1 = min(3, 5-py);
    int kx0 = max(0, 2-px), kx1 = min(3, 5-px);
    float acc = 0.f;
    for (int ci=0; ci<64; ci++){
      const float* wr = &ws[(oc*64+ci)*16];
      const float* xr = &xs[ci*16];
      for (int ky=ky0; ky<=ky1; ky++)
        for (int kx=kx0; kx<=kx1; kx++)
          acc += wr[ky*4+kx] * xr[(py+ky-2)*4 + (px+kx-2)];
    }
    vals[oc][pos] = acc;
  }
  __syncthreads();
  if (t < 10){
    float m = vals[t][0];
    #pragma unroll
    for (int p=1;p<25;p++) m = fmaxf(m, vals[t][p]);
    out[b*10 + t] = m + bias[t];
  }
  if (b == 0 && t == 255) out[20480] = nmsa[0] * (1.f/12845056.f);
}

extern "C" void kernel_launch(void* const* d_in, const int* in_sizes, int n_in,
                              void* d_out, int out_size, void* d_ws, size_t ws_size,
                              hipStream_t stream){
  const float* x  = (const float*)d_in[0];
  const float* w1 = (const float*)d_in[1];
  const float* w2 = (const float*)d_in[2];
  const float* w3 = (const float*)d_in[3];
  const float* w4 = (const float*)d_in[4];
  const float* w5 = (const float*)d_in[5];
  const float* w6 = (const float*)d_in[6];
  const float* w7 = (const float*)d_in[7];
  const float* g1 = (const float*)d_in[8];
  const float* b1 = (const float*)d_in[9];
  const float* g2 = (const float*)d_in[10];
  const float* b2 = (const float*)d_in[11];
  const float* g3 = (const float*)d_in[12];
  const float* b3 = (const float*)d_in[13];
  const float* g4 = (const float*)d_in[14];
  const float* b4 = (const float*)d_in[15];
  const float* g5 = (const float*)d_in[16];
  const float* b5 = (const float*)d_in[17];
  const float* g6 = (const float*)d_in[18];
  const float* b6 = (const float*)d_in[19];
  const float* b7 = (const float*)d_in[20];
  float* out = (float*)d_out;
  float* W = (float*)d_ws;

  // arena (floats): two 103MB buffers with reuse + stats region
  float* y1 = W;                 // S1
  float* y2 = W + (size_t)S1;    // S1
  float* p2 = W;                 // SP2 (y1 dead after conv2)
  float* y3 = W + (size_t)SP2;   // 32*196*NB (disjoint from p2)
  float* y4 = W + (size_t)S1;    // over y2 (dead after pool2)
  float* p4 = W;                 // 32*49*NB (disjoint from live y3)
  float* y5 = W + (size_t)S1;    // over y4 (dead after pool4)
  float* y6 = W;                 // over p4/p2 (dead)
  float* p6 = W + (size_t)S1;    // over y5 (dead after conv6)
  float* st = W + 2*(size_t)S1;  // 2048 floats: sums[6*128], coefs[6*128], nms

  float* cf = st + 768;
  float* nmsa = st + 1536;

  k_zero<<<8,256,0,stream>>>(st);

  k_conv1<<<6272,256,0,stream>>>(x, w1, y1);
  k_stats<16,784><<<dim3(64,16),256,0,stream>>>(y1, st + 0*128);
  k_fin<<<1,64,0,stream>>>(st + 0*128, g1, b1, cf + 0*128, 16, 1, 1.f/1605632.f);

  k_conv2<<<6272,256,0,stream>>>(y1, w2, cf + 0*128, y2);
  k_stats<16,784><<<dim3(64,16),256,0,stream>>>(y2, st + 1*128);
  k_fin<<<1,64,0,stream>>>(st + 1*128, g2, b2, cf + 1*128, 16, 1, 1.f/1605632.f);
  k_pool<16,28><<<25088,256,0,stream>>>(y2, cf + 1*128, p2);

  k_conv3<<<1568,256,0,stream>>>(p2, w3, y3);
  k_stats<32,196><<<dim3(64,32),256,0,stream>>>(y3, st + 2*128);
  k_fin<<<1,64,0,stream>>>(st + 2*128, g3, b3, cf + 2*128, 32, 3, 1.f/401408.f);
  k_nms<<<6272,256,0,stream>>>(y3, cf + 2*128, nmsa);

  k_conv4<<<784,256,0,stream>>>(y3, w4, cf + 2*128, y4);
  k_stats<32,196><<<dim3(64,32),256,0,stream>>>(y4, st + 3*128);
  k_fin<<<1,64,0,stream>>>(st + 3*128, g4, b4, cf + 3*128, 32, 31, 1.f/401408.f);
  k_pool<32,14><<<12544,256,0,stream>>>(y4, cf + 3*128, p4);

  k_conv5<<<512,256,0,stream>>>(p4, w5, y5);
  k_stats<64,49><<<dim3(64,64),256,0,stream>>>(y5, st + 4*128);
  k_fin<<<1,64,0,stream>>>(st + 4*128, g5, b5, cf + 4*128, 64, 63, 1.f/100352.f);

  k_conv6<<<512,256,0,stream>>>(y5, w6, cf + 4*128, y6);
  k_stats<64,49><<<dim3(64,64),256,0,stream>>>(y6, st + 5*128);
  k_fin<<<1,64,0,stream>>>(st + 5*128, g6, b6, cf + 5*128, 64, 63, 1.f/100352.f);
  k_pool6<<<8192,256,0,stream>>>(y6, cf + 5*128, p6);

  k_conv7<<<2048,256,0,stream>>>(p6, w7, b7, nmsa, out);
}

// Round 2
// 1279.638 us; speedup vs baseline: 1.7267x; 1.7267x over previous
//
#include <hip/hip_runtime.h>

static constexpr int NB = 2048;

// rotated-3x3 tap permutation: weight tap k of rotation r lands at patch position DST[r][k]
static constexpr int DST[8][9] = {
  {8,7,6,5,4,3,2,1,0},
  {5,8,7,2,4,6,1,0,3},
  {2,5,8,1,4,7,0,3,6},
  {1,2,5,0,4,8,3,6,7},
  {0,1,2,3,4,5,6,7,8},
  {3,0,1,6,4,2,7,8,5},
  {6,3,0,7,4,1,8,5,2},
  {7,6,3,8,4,0,5,2,1},
};

static constexpr int S1  = 2048*16*784;   // 25,690,112 floats
static constexpr int SP2 = 2048*16*196;   //  6,422,528

// ---------------- zero stats region ----------------
__global__ __launch_bounds__(256) void k_zero(float* st){
  int i = blockIdx.x*256 + threadIdx.x;
  if (i < 2048) st[i] = 0.f;
}

// ---------------- conv1: 1->16ch rotated, separate ----------------
__global__ __launch_bounds__(256) void k_conv1(const float* __restrict__ x,
                                               const float* __restrict__ w1,
                                               float* __restrict__ y1){
  int idx = blockIdx.x*256 + threadIdx.x;       // NB*784 exact
  int b = idx / 784, pix = idx - b*784;
  int py = pix / 28, px = pix - py*28;
  const float* xb = x + (size_t)b*784;
  float tap[9];
  #pragma unroll
  for (int d=0; d<9; d++){
    int dy = d/3 - 1, dx = d%3 - 1;
    int yy = py + dy, xx = px + dx;
    float v = 0.f;
    if (yy>=0 && yy<28 && xx>=0 && xx<28) v = xb[yy*28+xx];
    tap[d] = v;
  }
  float w[18];
  #pragma unroll
  for (int i=0;i<18;i++) w[i] = w1[i];
  float* yb = y1 + (size_t)b*12544 + pix;
  #pragma unroll
  for (int rot=0; rot<8; rot++){
    #pragma unroll
    for (int u=0; u<2; u++){
      float acc = 0.f;
      #pragma unroll
      for (int k=0;k<9;k++) acc += w[u*9+k]*tap[DST[rot][k]];
      yb[(rot*2+u)*784] = acc;
    }
  }
}

// ---------------- per-channel sum/sumsq ----------------
template<int C, int HW>
__global__ __launch_bounds__(256) void k_stats(const float* __restrict__ y, float* __restrict__ st){
  int c = blockIdx.y;
  const int N = NB*HW;
  float s=0.f, s2=0.f;
  for (int i = blockIdx.x*256 + threadIdx.x; i < N; i += gridDim.x*256){
    int b = i / HW, hw = i - b*HW;
    float v = y[((size_t)b*C + c)*HW + hw];
    s += v; s2 += v*v;
  }
  #pragma unroll
  for (int off=32; off; off>>=1){ s += __shfl_down(s, off); s2 += __shfl_down(s2, off); }
  __shared__ float sh[8];
  if ((threadIdx.x & 63) == 0){ sh[(threadIdx.x>>6)*2] = s; sh[(threadIdx.x>>6)*2+1] = s2; }
  __syncthreads();
  if (threadIdx.x == 0){
    atomicAdd(&st[c],    sh[0]+sh[2]+sh[4]+sh[6]);
    atomicAdd(&st[64+c], sh[1]+sh[3]+sh[5]+sh[7]);
  }
}

// ---------------- BN finalize: a = g*rsqrt(var+eps), b = beta - mu*a ----------------
__global__ void k_fin(const float* __restrict__ st, const float* __restrict__ g,
                      const float* __restrict__ be, float* __restrict__ coef,
                      int C, int gmask, float invN){
  int c = threadIdx.x;
  if (c >= C) return;
  float mu  = st[c]*invN;
  float var = st[64+c]*invN - mu*mu;
  float a = g[c & gmask] * rsqrtf(var + 1e-5f);
  coef[c]    = a;
  coef[64+c] = be[c & gmask] - mu*a;
}

// ---------------- conv2: 16->16 rotated non-separate, fused bn1+relu on read ----------------
// 2x2 pixel tile per thread; per-input-channel loop keeps live set small (no spills).
__global__ __launch_bounds__(256) void k_conv2(const float* __restrict__ y1,
                                               const float* __restrict__ w2,
                                               const float* __restrict__ coef,
                                               float* __restrict__ y2){
  __shared__ float ws[384];                 // 32 filters, padded stride 12
  __shared__ float ca[16], cb[16];
  for (int i=threadIdx.x; i<288; i+=256){
    int f = i/9, k = i - f*9;
    ws[f*12+k] = w2[i];
  }
  if (threadIdx.x < 16){ ca[threadIdx.x] = coef[threadIdx.x]; cb[threadIdx.x] = coef[64+threadIdx.x]; }
  __syncthreads();
  int tg = blockIdx.x*256 + threadIdx.x;    // 2048*196 = 401408 exact (1568 blocks)
  int b = tg / 196, tile = tg - b*196;
  int ty2 = (tile/14)*2, tx2 = (tile%14)*2;
  const float* src0 = y1 + (size_t)b*12544;
  float acc[16][4];
  #pragma unroll
  for (int o=0;o<16;o++){ acc[o][0]=0.f; acc[o][1]=0.f; acc[o][2]=0.f; acc[o][3]=0.f; }
  for (int ci=0; ci<16; ci++){
    float a = ca[ci], bo = cb[ci];
    const float* s2 = src0 + ci*784;
    float t[16];
    #pragma unroll
    for (int r=0;r<4;r++){
      int iy = ty2 - 1 + r;
      bool vy = (iy>=0 && iy<28);
      #pragma unroll
      for (int c2=0;c2<4;c2++){
        int ix = tx2 - 1 + c2;
        float v = 0.f;
        if (vy && ix>=0 && ix<28) v = fmaxf(s2[iy*28+ix]*a + bo, 0.f);
        t[r*4+c2] = v;
      }
    }
    int bb = ci>>1, ui = ci&1;
    #pragma unroll
    for (int rot=0; rot<8; rot++){
      int wc = (((bb - rot) & 7)<<1) | ui;
      #pragma unroll
      for (int u=0; u<2; u++){
        const float* wr = &ws[(u*16+wc)*12];
        float4 wA = *(const float4*)wr;
        float4 wB = *(const float4*)(wr+4);
        float w8 = wr[8];
        float wv[9] = {wA.x,wA.y,wA.z,wA.w,wB.x,wB.y,wB.z,wB.w,w8};
        #pragma unroll
        for (int k=0;k<9;k++){
          int d = DST[rot][k];
          int dy = d/3, dx = d - dy*3;
          float w = wv[k];
          acc[rot*2+u][0] += w*t[dy*4+dx];
          acc[rot*2+u][1] += w*t[dy*4+dx+1];
          acc[rot*2+u][2] += w*t[(dy+1)*4+dx];
          acc[rot*2+u][3] += w*t[(dy+1)*4+dx+1];
        }
      }
    }
  }
  float* ob = y2 + (size_t)b*12544 + ty2*28 + tx2;
  #pragma unroll
  for (int c=0;c<16;c++){
    float* dst = ob + c*784;
    *(float2*)dst      = make_float2(acc[c][0], acc[c][1]);
    *(float2*)(dst+28) = make_float2(acc[c][2], acc[c][3]);
  }
}

// ---------------- bn+relu+2x2 maxpool ----------------
template<int C, int HI>
__global__ __launch_bounds__(256) void k_pool(const float* __restrict__ y,
                                              const float* __restrict__ coef,
                                              float* __restrict__ p){
  constexpr int HO = HI/2;
  int idx = blockIdx.x*256 + threadIdx.x;       // exact
  int xo = idx % HO; int t1 = idx / HO;
  int yo = t1 % HO; int t2 = t1 / HO;
  int c = t2 % C;   int b = t2 / C;
  float a = coef[c], bo = coef[64+c];
  const float* src = y + ((size_t)b*C + c)*(HI*HI) + yo*2*HI + xo*2;
  float m = fmaxf(fmaxf(src[0]*a+bo, src[1]*a+bo), fmaxf(src[HI]*a+bo, src[HI+1]*a+bo));
  p[idx] = fmaxf(m, 0.f);
}

// ---------------- conv3: 16->32 rotated non-separate (input already normalized) ----------------
// 2x2 pixel tile; output channels split in two halves across blocks (u pair per block).
__global__ __launch_bounds__(256) void k_conv3(const float* __restrict__ p2,
                                               const float* __restrict__ w3,
                                               float* __restrict__ y3){
  __shared__ float ws[384];                 // 2 u's x 16 wc, padded stride 12
  int uh = blockIdx.x / 392;                // 0 or 1
  int inner = blockIdx.x - uh*392;
  for (int i=threadIdx.x; i<288; i+=256){
    int f = i/9, k = i - f*9;
    ws[f*12+k] = w3[uh*288 + i];
  }
  __syncthreads();
  int tg = inner*256 + threadIdx.x;         // 2048*49 = 100352 exact (392 blocks)
  int b = tg / 49, tile = tg - b*49;
  int ty2 = (tile/7)*2, tx2 = (tile%7)*2;
  const float* src0 = p2 + (size_t)b*3136;
  float acc[16][4];
  #pragma unroll
  for (int o=0;o<16;o++){ acc[o][0]=0.f; acc[o][1]=0.f; acc[o][2]=0.f; acc[o][3]=0.f; }
  for (int ci=0; ci<16; ci++){
    const float* s2 = src0 + ci*196;
    float t[16];
    #pragma unroll
    for (int r=0;r<4;r++){
      int iy = ty2 - 1 + r;
      bool vy = (iy>=0 && iy<14);
      #pragma unroll
      for (int c2=0;c2<4;c2++){
        int ix = tx2 - 1 + c2;
        float v = 0.f;
        if (vy && ix>=0 && ix<14) v = s2[iy*14+ix];
        t[r*4+c2] = v;
      }
    }
    int bb = ci>>1, ui = ci&1;
    #pragma unroll
    for (int rot=0; rot<8; rot++){
      int wc = (((bb - rot) & 7)<<1) | ui;
      #pragma unroll
      for (int ul=0; ul<2; ul++){
        const float* wr = &ws[(ul*16+wc)*12];
        float4 wA = *(const float4*)wr;
        float4 wB = *(const float4*)(wr+4);
        float w8 = wr[8];
        float wv[9] = {wA.x,wA.y,wA.z,wA.w,wB.x,wB.y,wB.z,wB.w,w8};
        #pragma unroll
        for (int k=0;k<9;k++){
          int d = DST[rot][k];
          int dy = d/3, dx = d - dy*3;
          float w = wv[k];
          acc[rot*2+ul][0] += w*t[dy*4+dx];
          acc[rot*2+ul][1] += w*t[dy*4+dx+1];
          acc[rot*2+ul][2] += w*t[(dy+1)*4+dx];
          acc[rot*2+ul][3] += w*t[(dy+1)*4+dx+1];
        }
      }
    }
  }
  float* ob = y3 + (size_t)b*6272 + ty2*14 + tx2;
  #pragma unroll
  for (int rot=0;rot<8;rot++){
    #pragma unroll
    for (int ul=0;ul<2;ul++){
      float* dst = ob + (rot*4 + uh*2 + ul)*196;
      *(float2*)dst      = make_float2(acc[rot*2+ul][0], acc[rot*2+ul][1]);
      *(float2*)(dst+14) = make_float2(acc[rot*2+ul][2], acc[rot*2+ul][3]);
    }
  }
}

// ---------------- nms: sum of bn3+relu values != rotation-group max ----------------
__global__ __launch_bounds__(256) void k_nms(const float* __restrict__ y3,
                                             const float* __restrict__ coef,
                                             float* __restrict__ accum){
  int idx = blockIdx.x*256 + threadIdx.x;       // NB*4*196 exact
  int hw = idx % 196; int t1 = idx / 196;
  int c4 = t1 & 3;    int b = t1 >> 2;
  const float* base = y3 + ((size_t)b*32 + c4*8)*196 + hw;
  float v[8]; float vmax = -1e30f;
  #pragma unroll
  for (int r=0;r<8;r++){
    int c = c4*8 + r;
    float z = fmaxf(base[r*196]*coef[c] + coef[64+c], 0.f);
    v[r] = z;
    vmax = fmaxf(vmax, z);
  }
  float local = 0.f;
  #pragma unroll
  for (int r=0;r<8;r++) local += (v[r] != vmax) ? v[r] : 0.f;
  #pragma unroll
  for (int off=32; off; off>>=1) local += __shfl_down(local, off);
  __shared__ float sh[4];
  if ((threadIdx.x & 63) == 0) sh[threadIdx.x>>6] = local;
  __syncthreads();
  if (threadIdx.x == 0) atomicAdd(accum, sh[0]+sh[1]+sh[2]+sh[3]);
}

// ---------------- conv4: 32->32 standard, fused bn3+relu; 2x2 pixel tile, 16-oc half ----------------
__global__ __launch_bounds__(256) void k_conv4(const float* __restrict__ y3,
                                               const float* __restrict__ w4,
                                               const float* __restrict__ coef,
                                               float* __restrict__ y4){
  __shared__ float ws[4608];
  __shared__ float ca[32], cb[32];
  int ohalf = blockIdx.x / 392;
  int inner = blockIdx.x - ohalf*392;
  for (int i=threadIdx.x; i<4608; i+=256) ws[i] = w4[ohalf*4608 + i];
  if (threadIdx.x < 32){ ca[threadIdx.x] = coef[threadIdx.x]; cb[threadIdx.x] = coef[64+threadIdx.x]; }
  __syncthreads();
  int tg = inner*256 + threadIdx.x;
  int b = tg / 49, tile = tg - b*49;
  int ty = tile/7;
  int ty2 = ty*2, tx2 = (tile - ty*7)*2;
  const float* src = y3 + (size_t)b*6272;
  float acc[16][4];
  #pragma unroll
  for (int o=0;o<16;o++){ acc[o][0]=0.f; acc[o][1]=0.f; acc[o][2]=0.f; acc[o][3]=0.f; }
  for (int ci=0; ci<32; ci++){
    float a = ca[ci], bo = cb[ci];
    const float* s2 = src + ci*196;
    float t[16];
    #pragma unroll
    for (int r=0;r<4;r++){
      int iy = ty2 - 1 + r;
      bool vy = (iy>=0 && iy<14);
      #pragma unroll
      for (int c2=0;c2<4;c2++){
        int ix = tx2 - 1 + c2;
        float v = 0.f;
        if (vy && ix>=0 && ix<14) v = fmaxf(s2[iy*14+ix]*a + bo, 0.f);
        t[r*4+c2] = v;
      }
    }
    #pragma unroll
    for (int o=0;o<16;o++){
      const float* wr = &ws[(o*32+ci)*9];
      #pragma unroll
      for (int k=0;k<9;k++){
        float w = wr[k];
        int dy = k/3, dx = k - dy*3;
        acc[o][0] += w*t[dy*4+dx];
        acc[o][1] += w*t[dy*4+dx+1];
        acc[o][2] += w*t[(dy+1)*4+dx];
        acc[o][3] += w*t[(dy+1)*4+dx+1];
      }
    }
  }
  #pragma unroll
  for (int o=0;o<16;o++){
    float* dst = y4 + ((size_t)b*32 + ohalf*16 + o)*196;
    dst[ty2*14 + tx2]       = acc[o][0];
    dst[ty2*14 + tx2+1]     = acc[o][1];
    dst[(ty2+1)*14 + tx2]   = acc[o][2];
    dst[(ty2+1)*14 + tx2+1] = acc[o][3];
  }
}

// ---------------- conv5: 32->64 standard, raw input; 2x2 tile, 16-oc quarter ----------------
__global__ __launch_bounds__(256) void k_conv5(const float* __restrict__ p4,
                                               const float* __restrict__ w5,
                                               float* __restrict__ y5){
  __shared__ float ws[4608];
  int ohq = blockIdx.x >> 7;
  int inner = blockIdx.x & 127;
  for (int i=threadIdx.x; i<4608; i+=256) ws[i] = w5[ohq*4608 + i];
  __syncthreads();
  int tg = inner*256 + threadIdx.x;
  int b = tg >> 4, tile = tg & 15;
  int ty2 = (tile>>2)*2, tx2 = (tile&3)*2;
  const float* src = p4 + (size_t)b*1568;   // 32*49
  float acc[16][4];
  #pragma unroll
  for (int o=0;o<16;o++){ acc[o][0]=0.f; acc[o][1]=0.f; acc[o][2]=0.f; acc[o][3]=0.f; }
  for (int ci=0; ci<32; ci++){
    const float* s2 = src + ci*49;
    float t[16];
    #pragma unroll
    for (int r=0;r<4;r++){
      int iy = ty2 - 1 + r;
      bool vy = (iy>=0 && iy<7);
      #pragma unroll
      for (int c2=0;c2<4;c2++){
        int ix = tx2 - 1 + c2;
        float v = 0.f;
        if (vy && ix>=0 && ix<7) v = s2[iy*7+ix];
        t[r*4+c2] = v;
      }
    }
    #pragma unroll
    for (int o=0;o<16;o++){
      const float* wr = &ws[(o*32+ci)*9];
      #pragma unroll
      for (int k=0;k<9;k++){
        float w = wr[k];
        int dy = k/3, dx = k - dy*3;
        acc[o][0] += w*t[dy*4+dx];
        acc[o][1] += w*t[dy*4+dx+1];
        acc[o][2] += w*t[(dy+1)*4+dx];
        acc[o][3] += w*t[(dy+1)*4+dx+1];
      }
    }
  }
  #pragma unroll
  for (int o=0;o<16;o++){
    float* dst = y5 + ((size_t)b*64 + ohq*16 + o)*49;
    #pragma unroll
    for (int p=0;p<4;p++){
      int oy = ty2 + (p>>1), ox = tx2 + (p&1);
      if (oy<7 && ox<7) dst[oy*7+ox] = acc[o][p];
    }
  }
}

// ---------------- conv6: 64->64 standard, fused bn5+relu; 2x2 tile, 16-oc quarter ----------------
__global__ __launch_bounds__(256) void k_conv6(const float* __restrict__ y5,
                                               const float* __restrict__ w6,
                                               const float* __restrict__ coef,
                                               float* __restrict__ y6){
  __shared__ float ws[9216];
  __shared__ float ca[64], cb[64];
  int ohq = blockIdx.x >> 7;
  int inner = blockIdx.x & 127;
  for (int i=threadIdx.x; i<9216; i+=256) ws[i] = w6[ohq*9216 + i];
  if (threadIdx.x < 64){ ca[threadIdx.x] = coef[threadIdx.x]; cb[threadIdx.x] = coef[64+threadIdx.x]; }
  __syncthreads();
  int tg = inner*256 + threadIdx.x;
  int b = tg >> 4, tile = tg & 15;
  int ty2 = (tile>>2)*2, tx2 = (tile&3)*2;
  const float* src = y5 + (size_t)b*3136;   // 64*49
  float acc[16][4];
  #pragma unroll
  for (int o=0;o<16;o++){ acc[o][0]=0.f; acc[o][1]=0.f; acc[o][2]=0.f; acc[o][3]=0.f; }
  for (int ci=0; ci<64; ci++){
    float a = ca[ci], bo = cb[ci];
    const float* s2 = src + ci*49;
    float t[16];
    #pragma unroll
    for (int r=0;r<4;r++){
      int iy = ty2 - 1 + r;
      bool vy = (iy>=0 && iy<7);
      #pragma unroll
      for (int c2=0;c2<4;c2++){
        int ix = tx2 - 1 + c2;
        float v = 0.f;
        if (vy && ix>=0 && ix<7) v = fmaxf(s2[iy*7+ix]*a + bo, 0.f);
        t[r*4+c2] = v;
      }
    }
    #pragma unroll
    for (int o=0;o<16;o++){
      const float* wr = &ws[(o*64+ci)*9];
      #pragma unroll
      for (int k=0;k<9;k++){
        float w = wr[k];
        int dy = k/3, dx = k - dy*3;
        acc[o][0] += w*t[dy*4+dx];
        acc[o][1] += w*t[dy*4+dx+1];
        acc[o][2] += w*t[(dy+1)*4+dx];
        acc[o][3] += w*t[(dy+1)*4+dx+1];
      }
    }
  }
  #pragma unroll
  for (int o=0;o<16;o++){
    float* dst = y6 + ((size_t)b*64 + ohq*16 + o)*49;
    #pragma unroll
    for (int p=0;p<4;p++){
      int oy = ty2 + (p>>1), ox = tx2 + (p&1);
      if (oy<7 && ox<7) dst[oy*7+ox] = acc[o][p];
    }
  }
}

// ---------------- bn6+relu + 2x2 pool pad 1 (7 -> 4) ----------------
__global__ __launch_bounds__(256) void k_pool6(const float* __restrict__ y,
                                               const float* __restrict__ coef,
                                               float* __restrict__ p){
  int idx = blockIdx.x*256 + threadIdx.x;       // NB*64*16 exact
  int xo = idx & 3; int t1 = idx >> 2;
  int yo = t1 & 3;  int t2 = t1 >> 2;
  int c = t2 & 63;  int b = t2 >> 6;
  float a = coef[c], bo = coef[64+c];
  const float* src = y + ((size_t)b*64 + c)*49;
  float m = -1e30f;
  #pragma unroll
  for (int dy=0;dy<2;dy++){
    int iy = yo*2 - 1 + dy;
    if (iy < 0 || iy >= 7) continue;
    #pragma unroll
    for (int dx=0;dx<2;dx++){
      int ix = xo*2 - 1 + dx;
      if (ix < 0 || ix >= 7) continue;
      m = fmaxf(m, src[iy*7+ix]*a + bo);
    }
  }
  p[idx] = fmaxf(m, 0.f);
}

// ---------------- conv7 (pad 2, 4x4 kernel, 5x5 out) + bias + global max + nms write ----------------
__global__ __launch_bounds__(256) void k_conv7(const float* __restrict__ p6,
                                               const float* __restrict__ w7,
                                               const float* __restrict__ bias,
                                               const float* __restrict__ nmsa,
                                               float* __restrict__ out){
  __shared__ float ws[10240];
  __shared__ float xs[1024];
  __shared__ float vals[10][25];
  int b = blockIdx.x;
  for (int i=threadIdx.x; i<10240; i+=256) ws[i] = w7[i];
  for (int i=threadIdx.x; i<1024; i+=256) xs[i] = p6[(size_t)b*1024 + i];
  __syncthreads();
  int t = threadIdx.x;
  if (t < 250){
    int oc = t/25, pos = t - oc*25;
    int py = pos/5, px = pos - py*5;
    int ky0 = max(0, 2-py), ky1 = min(3, 5-py);
    int kx0 = max(0, 2-px), kx1 = min(3, 5-px);
    float acc = 0.f;
    for (int ci=0; ci<64; ci++){
      const float* wr = &ws[(oc*64+ci)*16];
      const float* xr = &xs[ci*16];
      for (int ky=ky0; ky<=ky1; ky++)
        for (int kx=kx0; kx<=kx1; kx++)
          acc += wr[ky*4+kx] * xr[(py+ky-2)*4 + (px+kx-2)];
    }
    vals[oc][pos] = acc;
  }
  __syncthreads();
  if (t < 10){
    float m = vals[t][0];
    #pragma unroll
    for (int p=1;p<25;p++) m = fmaxf(m, vals[t][p]);
    out[b*10 + t] = m + bias[t];
  }
  if (b == 0 && t == 255) out[20480] = nmsa[0] * (1.f/12845056.f);
}

extern "C" void kernel_launch(void* const* d_in, const int* in_sizes, int n_in,
                              void* d_out, int out_size, void* d_ws, size_t ws_size,
                              hipStream_t stream){
  const float* x  = (const float*)d_in[0];
  const float* w1 = (const float*)d_in[1];
  const float* w2 = (const float*)d_in[2];
  const float* w3 = (const float*)d_in[3];
  const float* w4 = (const float*)d_in[4];
  const float* w5 = (const float*)d_in[5];
  const float* w6 = (const float*)d_in[6];
  const float* w7 = (const float*)d_in[7];
  const float* g1 = (const float*)d_in[8];
  const float* b1 = (const float*)d_in[9];
  const float* g2 = (const float*)d_in[10];
  const float* b2 = (const float*)d_in[11];
  const float* g3 = (const float*)d_in[12];
  const float* b3 = (const float*)d_in[13];
  const float* g4 = (const float*)d_in[14];
  const float* b4 = (const float*)d_in[15];
  const float* g5 = (const float*)d_in[16];
  const float* b5 = (const float*)d_in[17];
  const float* g6 = (const float*)d_in[18];
  const float* b6 = (const float*)d_in[19];
  const float* b7 = (const float*)d_in[20];
  float* out = (float*)d_out;
  float* W = (float*)d_ws;

  // arena (floats): two 103MB buffers with reuse + stats region
  float* y1 = W;                 // S1
  float* y2 = W + (size_t)S1;    // S1
  float* p2 = W;                 // SP2 (y1 dead after conv2)
  float* y3 = W + (size_t)SP2;   // 32*196*NB (disjoint from p2)
  float* y4 = W + (size_t)S1;    // over y2 (dead after pool2)
  float* p4 = W;                 // 32*49*NB (disjoint from live y3)
  float* y5 = W + (size_t)S1;    // over y4 (dead after pool4)
  float* y6 = W;                 // over p4/p2 (dead)
  float* p6 = W + (size_t)S1;    // over y5 (dead after conv6)
  float* st = W + 2*(size_t)S1;  // 2048 floats: sums[6*128], coefs[6*128], nms

  float* cf = st + 768;
  float* nmsa = st + 1536;

  k_zero<<<8,256,0,stream>>>(st);

  k_conv1<<<6272,256,0,stream>>>(x, w1, y1);
  k_stats<16,784><<<dim3(64,16),256,0,stream>>>(y1, st + 0*128);
  k_fin<<<1,64,0,stream>>>(st + 0*128, g1, b1, cf + 0*128, 16, 1, 1.f/1605632.f);

  k_conv2<<<1568,256,0,stream>>>(y1, w2, cf + 0*128, y2);
  k_stats<16,784><<<dim3(64,16),256,0,stream>>>(y2, st + 1*128);
  k_fin<<<1,64,0,stream>>>(st + 1*128, g2, b2, cf + 1*128, 16, 1, 1.f/1605632.f);
  k_pool<16,28><<<25088,256,0,stream>>>(y2, cf + 1*128, p2);

  k_conv3<<<784,256,0,stream>>>(p2, w3, y3);
  k_stats<32,196><<<dim3(64,32),256,0,stream>>>(y3, st + 2*128);
  k_fin<<<1,64,0,stream>>>(st + 2*128, g3, b3, cf + 2*128, 32, 3, 1.f/401408.f);
  k_nms<<<6272,256,0,stream>>>(y3, cf + 2*128, nmsa);

  k_conv4<<<784,256,0,stream>>>(y3, w4, cf + 2*128, y4);
  k_stats<32,196><<<dim3(64,32),256,0,stream>>>(y4, st + 3*128);
  k_fin<<<1,64,0,stream>>>(st + 3*128, g4, b4, cf + 3*128, 32, 31, 1.f/401408.f);
  k_pool<32,14><<<12544,256,0,stream>>>(y4, cf + 3*128, p4);

  k_conv5<<<512,256,0,stream>>>(p4, w5, y5);
  k_stats<64,49><<<dim3(64,64),256,0,stream>>>(y5, st + 4*128);
  k_fin<<<1,64,0,stream>>>(st + 4*128, g5, b5, cf + 4*128, 64, 63, 1.f/100352.f);

  k_conv6<<<512,256,0,stream>>>(y5, w6, cf + 4*128, y6);
  k_stats<64,49><<<dim3(64,64),256,0,stream>>>(y6, st + 5*128);
  k_fin<<<1,64,0,stream>>>(st + 5*128, g6, b6, cf + 5*128, 64, 63, 1.f/100352.f);
  k_pool6<<<8192,256,0,stream>>>(y6, cf + 5*128, p6);

  k_conv7<<<2048,256,0,stream>>>(p6, w7, b7, nmsa, out);
}

// Round 3
// 1206.843 us; speedup vs baseline: 1.8308x; 1.0603x over previous
//
#include <hip/hip_runtime.h>

static constexpr int NB = 2048;

// rotated-3x3 tap permutation: weight tap k of rotation r lands at patch position DST[r][k]
static constexpr int DST[8][9] = {
  {8,7,6,5,4,3,2,1,0},
  {5,8,7,2,4,6,1,0,3},
  {2,5,8,1,4,7,0,3,6},
  {1,2,5,0,4,8,3,6,7},
  {0,1,2,3,4,5,6,7,8},
  {3,0,1,6,4,2,7,8,5},
  {6,3,0,7,4,1,8,5,2},
  {7,6,3,8,4,0,5,2,1},
};

// ---------------- zero stats region ----------------
__global__ __launch_bounds__(256) void k_zero(float* st){
  int i = blockIdx.x*256 + threadIdx.x;
  if (i < 2048) st[i] = 0.f;
}

// ---------------- stats of y1 = rotconv1(x), y1 never materialized ----------------
__global__ __launch_bounds__(256) void k_stats1(const float* __restrict__ x,
                                                const float* __restrict__ w1,
                                                float* __restrict__ st){
  __shared__ float wp[192];                  // permuted conv1 weights, stride 12
  __shared__ float red[4][32];
  for (int i=threadIdx.x; i<144; i+=256){
    int rot = i/18, rem = i-rot*18, u = rem/9, k = rem-u*9;
    wp[(rot*2+u)*12 + DST[rot][k]] = w1[u*9+k];
  }
  __syncthreads();
  float s[16], s2[16];
  #pragma unroll
  for (int o=0;o<16;o++){ s[o]=0.f; s2[o]=0.f; }
  for (int idx = blockIdx.x*256 + threadIdx.x; idx < NB*784; idx += 512*256){
    int b = idx/784, pix = idx-b*784;
    int py = pix/28, px = pix-py*28;
    const float* xb = x + (size_t)b*784;
    float tap[9];
    #pragma unroll
    for (int d=0; d<9; d++){
      int dy = d/3-1, dx = d%3-1;
      int yy = py+dy, xx = px+dx;
      tap[d] = (yy>=0 && yy<28 && xx>=0 && xx<28) ? xb[yy*28+xx] : 0.f;
    }
    #pragma unroll
    for (int ci=0; ci<16; ci++){
      float y = 0.f;
      #pragma unroll
      for (int d=0; d<9; d++) y += wp[ci*12+d]*tap[d];
      s[ci] += y; s2[ci] += y*y;
    }
  }
  int wid = threadIdx.x>>6;
  #pragma unroll
  for (int o=0;o<16;o++){
    float a = s[o], b2 = s2[o];
    #pragma unroll
    for (int off=32; off; off>>=1){ a += __shfl_down(a,off); b2 += __shfl_down(b2,off); }
    if ((threadIdx.x&63)==0){ red[wid][o] = a; red[wid][16+o] = b2; }
  }
  __syncthreads();
  if (threadIdx.x < 32){
    float v = red[0][threadIdx.x]+red[1][threadIdx.x]+red[2][threadIdx.x]+red[3][threadIdx.x];
    int c = threadIdx.x & 15;
    atomicAdd(&st[(threadIdx.x<16)? c : 64+c], v);
  }
}

// ---------------- BN finalize: a = g*rsqrt(var+eps), b = beta - mu*a ----------------
__global__ void k_fin(const float* __restrict__ st, const float* __restrict__ g,
                      const float* __restrict__ be, float* __restrict__ coef,
                      int C, int gmask, float invN){
  int c = threadIdx.x;
  if (c >= C) return;
  float mu  = st[c]*invN;
  float var = st[64+c]*invN - mu*mu;
  float a = g[c & gmask] * rsqrtf(var + 1e-5f);
  coef[c]    = a;
  coef[64+c] = be[c & gmask] - mu*a;
}

// ---------------- conv2: recompute y1 from x, rot-conv 16->16, fused stats + raw pool ----------------
__global__ __launch_bounds__(256) void k_conv2(const float* __restrict__ x,
                                               const float* __restrict__ w1,
                                               const float* __restrict__ w2,
                                               const float* __restrict__ coef,
                                               float* __restrict__ p2,
                                               float* __restrict__ st){
  __shared__ float wp[192];                 // permuted conv1 weights
  __shared__ float ws[384];                 // conv2 weights, stride 12
  __shared__ float ca[16], cb[16];
  __shared__ float red[4][32];
  for (int i=threadIdx.x; i<144; i+=256){
    int rot = i/18, rem = i-rot*18, u = rem/9, k = rem-u*9;
    wp[(rot*2+u)*12 + DST[rot][k]] = w1[u*9+k];
  }
  for (int i=threadIdx.x; i<288; i+=256){
    int f = i/9, k = i-f*9;
    ws[f*12+k] = w2[i];
  }
  if (threadIdx.x < 16){ ca[threadIdx.x] = coef[threadIdx.x]; cb[threadIdx.x] = coef[64+threadIdx.x]; }
  __syncthreads();
  int tg = blockIdx.x*256 + threadIdx.x;    // 2048*196 (1568 blocks)
  int b = tg / 196, tile = tg - b*196;
  int ty2 = (tile/14)*2, tx2 = (tile%14)*2;
  const float* xb = x + (size_t)b*784;
  // 6x6 x patch, zero padded
  float xp[36];
  #pragma unroll
  for (int r=0;r<6;r++){
    int iy = ty2-2+r;
    bool vy = (iy>=0 && iy<28);
    #pragma unroll
    for (int c=0;c<6;c++){
      int ix = tx2-2+c;
      xp[r*6+c] = (vy && ix>=0 && ix<28) ? xb[iy*28+ix] : 0.f;
    }
  }
  // pixel validity of the 4x4 y1 patch
  float vm[16];
  #pragma unroll
  for (int r=0;r<4;r++){
    int iy = ty2-1+r;
    #pragma unroll
    for (int c=0;c<4;c++){
      int ix = tx2-1+c;
      vm[r*4+c] = (iy>=0 && iy<28 && ix>=0 && ix<28) ? 1.f : 0.f;
    }
  }
  float acc[16][4];
  #pragma unroll
  for (int o=0;o<16;o++){ acc[o][0]=0.f; acc[o][1]=0.f; acc[o][2]=0.f; acc[o][3]=0.f; }
  for (int ci=0; ci<16; ci++){
    float a = ca[ci], bo = cb[ci];
    float wv1[9];
    #pragma unroll
    for (int d=0; d<9; d++) wv1[d] = wp[ci*12+d];
    float t[16];
    #pragma unroll
    for (int r=0;r<4;r++){
      #pragma unroll
      for (int c=0;c<4;c++){
        float y = 0.f;
        #pragma unroll
        for (int d=0; d<9; d++){
          int dy = d/3, dx = d-dy*3;
          y += wv1[d]*xp[(r+dy)*6 + (c+dx)];
        }
        t[r*4+c] = vm[r*4+c]*fmaxf(a*y + bo, 0.f);
      }
    }
    int bb = ci>>1, ui = ci&1;
    #pragma unroll
    for (int rot=0; rot<8; rot++){
      int wc = (((bb - rot) & 7)<<1) | ui;
      #pragma unroll
      for (int u=0; u<2; u++){
        const float* wr = &ws[(u*16+wc)*12];
        float wv[9];
        #pragma unroll
        for (int k=0;k<9;k++) wv[k] = wr[k];
        #pragma unroll
        for (int k=0;k<9;k++){
          int d = DST[rot][k];
          int dy = d/3, dx = d-dy*3;
          float w = wv[k];
          acc[rot*2+u][0] += w*t[dy*4+dx];
          acc[rot*2+u][1] += w*t[dy*4+dx+1];
          acc[rot*2+u][2] += w*t[(dy+1)*4+dx];
          acc[rot*2+u][3] += w*t[(dy+1)*4+dx+1];
        }
      }
    }
  }
  // epilogue: raw 2x2 max pool + per-channel stats
  int wid = threadIdx.x>>6;
  #pragma unroll
  for (int o=0;o<16;o++){
    float m = fmaxf(fmaxf(acc[o][0],acc[o][1]), fmaxf(acc[o][2],acc[o][3]));
    p2[((size_t)b*16+o)*196 + tile] = m;
    float s  = acc[o][0]+acc[o][1]+acc[o][2]+acc[o][3];
    float s2 = acc[o][0]*acc[o][0]+acc[o][1]*acc[o][1]+acc[o][2]*acc[o][2]+acc[o][3]*acc[o][3];
    #pragma unroll
    for (int off=32; off; off>>=1){ s += __shfl_down(s,off); s2 += __shfl_down(s2,off); }
    if ((threadIdx.x&63)==0){ red[wid][o] = s; red[wid][16+o] = s2; }
  }
  __syncthreads();
  if (threadIdx.x < 32){
    float v = red[0][threadIdx.x]+red[1][threadIdx.x]+red[2][threadIdx.x]+red[3][threadIdx.x];
    int c = threadIdx.x & 15;
    atomicAdd(&st[(threadIdx.x<16)? c : 64+c], v);
  }
}

// ---------------- conv3: 16->32 rotated non-separate, bn2+relu on read, fused stats ----------------
__global__ __launch_bounds__(256) void k_conv3(const float* __restrict__ p2,
                                               const float* __restrict__ w3,
                                               const float* __restrict__ coef,
                                               float* __restrict__ y3,
                                               float* __restrict__ st){
  __shared__ float ws[384];
  __shared__ float ca[16], cb[16];
  __shared__ float red[4][32];
  int uh = blockIdx.x / 392;
  int inner = blockIdx.x - uh*392;
  for (int i=threadIdx.x; i<288; i+=256){
    int f = i/9, k = i-f*9;
    ws[f*12+k] = w3[uh*288 + i];
  }
  if (threadIdx.x < 16){ ca[threadIdx.x] = coef[threadIdx.x]; cb[threadIdx.x] = coef[64+threadIdx.x]; }
  __syncthreads();
  int tg = inner*256 + threadIdx.x;
  int b = tg / 49, tile = tg - b*49;
  int ty2 = (tile/7)*2, tx2 = (tile%7)*2;
  const float* src0 = p2 + (size_t)b*3136;
  float acc[16][4];
  #pragma unroll
  for (int o=0;o<16;o++){ acc[o][0]=0.f; acc[o][1]=0.f; acc[o][2]=0.f; acc[o][3]=0.f; }
  for (int ci=0; ci<16; ci++){
    float a = ca[ci], bo = cb[ci];
    const float* s2p = src0 + ci*196;
    float t[16];
    #pragma unroll
    for (int r=0;r<4;r++){
      int iy = ty2-1+r;
      bool vy = (iy>=0 && iy<14);
      #pragma unroll
      for (int c2=0;c2<4;c2++){
        int ix = tx2-1+c2;
        float v = 0.f;
        if (vy && ix>=0 && ix<14) v = fmaxf(s2p[iy*14+ix]*a + bo, 0.f);
        t[r*4+c2] = v;
      }
    }
    int bb = ci>>1, ui = ci&1;
    #pragma unroll
    for (int rot=0; rot<8; rot++){
      int wc = (((bb - rot) & 7)<<1) | ui;
      #pragma unroll
      for (int ul=0; ul<2; ul++){
        const float* wr = &ws[(ul*16+wc)*12];
        float wv[9];
        #pragma unroll
        for (int k=0;k<9;k++) wv[k] = wr[k];
        #pragma unroll
        for (int k=0;k<9;k++){
          int d = DST[rot][k];
          int dy = d/3, dx = d-dy*3;
          float w = wv[k];
          acc[rot*2+ul][0] += w*t[dy*4+dx];
          acc[rot*2+ul][1] += w*t[dy*4+dx+1];
          acc[rot*2+ul][2] += w*t[(dy+1)*4+dx];
          acc[rot*2+ul][3] += w*t[(dy+1)*4+dx+1];
        }
      }
    }
  }
  float* ob = y3 + (size_t)b*6272 + ty2*14 + tx2;
  int wid = threadIdx.x>>6;
  #pragma unroll
  for (int rot=0;rot<8;rot++){
    #pragma unroll
    for (int ul=0;ul<2;ul++){
      int j = rot*2+ul;
      float* dst = ob + (rot*4 + uh*2 + ul)*196;
      *(float2*)dst      = make_float2(acc[j][0], acc[j][1]);
      *(float2*)(dst+14) = make_float2(acc[j][2], acc[j][3]);
      float s  = acc[j][0]+acc[j][1]+acc[j][2]+acc[j][3];
      float sq = acc[j][0]*acc[j][0]+acc[j][1]*acc[j][1]+acc[j][2]*acc[j][2]+acc[j][3]*acc[j][3];
      #pragma unroll
      for (int off=32; off; off>>=1){ s += __shfl_down(s,off); sq += __shfl_down(sq,off); }
      if ((threadIdx.x&63)==0){ red[wid][j] = s; red[wid][16+j] = sq; }
    }
  }
  __syncthreads();
  if (threadIdx.x < 32){
    float v = red[0][threadIdx.x]+red[1][threadIdx.x]+red[2][threadIdx.x]+red[3][threadIdx.x];
    int j = threadIdx.x & 15;
    int c = (j>>1)*4 + uh*2 + (j&1);
    atomicAdd(&st[(threadIdx.x<16)? c : 64+c], v);
  }
}

// ---------------- nms ----------------
__global__ __launch_bounds__(256) void k_nms(const float* __restrict__ y3,
                                             const float* __restrict__ coef,
                                             float* __restrict__ accum){
  int idx = blockIdx.x*256 + threadIdx.x;       // NB*4*196 exact
  int hw = idx % 196; int t1 = idx / 196;
  int c4 = t1 & 3;    int b = t1 >> 2;
  const float* base = y3 + ((size_t)b*32 + c4*8)*196 + hw;
  float v[8]; float vmax = -1e30f;
  #pragma unroll
  for (int r=0;r<8;r++){
    int c = c4*8 + r;
    float z = fmaxf(base[r*196]*coef[c] + coef[64+c], 0.f);
    v[r] = z;
    vmax = fmaxf(vmax, z);
  }
  float local = 0.f;
  #pragma unroll
  for (int r=0;r<8;r++) local += (v[r] != vmax) ? v[r] : 0.f;
  #pragma unroll
  for (int off=32; off; off>>=1) local += __shfl_down(local, off);
  __shared__ float sh[4];
  if ((threadIdx.x & 63) == 0) sh[threadIdx.x>>6] = local;
  __syncthreads();
  if (threadIdx.x == 0) atomicAdd(accum, sh[0]+sh[1]+sh[2]+sh[3]);
}

// ---------------- conv4: 32->32, bn3+relu on read, 8-oc groups, fused stats + raw pool ----------------
__global__ __launch_bounds__(256) void k_conv4(const float* __restrict__ y3,
                                               const float* __restrict__ w4,
                                               const float* __restrict__ coef,
                                               float* __restrict__ p4,
                                               float* __restrict__ st){
  __shared__ float ws[2304];
  __shared__ float ca[32], cb[32];
  __shared__ float red[4][16];
  int og = blockIdx.x / 392;                 // 0..3
  int inner = blockIdx.x - og*392;
  for (int i=threadIdx.x; i<2304; i+=256) ws[i] = w4[og*2304 + i];
  if (threadIdx.x < 32){ ca[threadIdx.x] = coef[threadIdx.x]; cb[threadIdx.x] = coef[64+threadIdx.x]; }
  __syncthreads();
  int tg = inner*256 + threadIdx.x;
  int b = tg / 49, tile = tg - b*49;
  int ty2 = (tile/7)*2, tx2 = (tile%7)*2;
  const float* src = y3 + (size_t)b*6272;
  float acc[8][4];
  #pragma unroll
  for (int o=0;o<8;o++){ acc[o][0]=0.f; acc[o][1]=0.f; acc[o][2]=0.f; acc[o][3]=0.f; }
  for (int ci=0; ci<32; ci++){
    float a = ca[ci], bo = cb[ci];
    const float* s2p = src + ci*196;
    float t[16];
    #pragma unroll
    for (int r=0;r<4;r++){
      int iy = ty2-1+r;
      bool vy = (iy>=0 && iy<14);
      #pragma unroll
      for (int c2=0;c2<4;c2++){
        int ix = tx2-1+c2;
        float v = 0.f;
        if (vy && ix>=0 && ix<14) v = fmaxf(s2p[iy*14+ix]*a + bo, 0.f);
        t[r*4+c2] = v;
      }
    }
    #pragma unroll
    for (int o=0;o<8;o++){
      const float* wr = &ws[(o*32+ci)*9];
      #pragma unroll
      for (int k=0;k<9;k++){
        float w = wr[k];
        int dy = k/3, dx = k-dy*3;
        acc[o][0] += w*t[dy*4+dx];
        acc[o][1] += w*t[dy*4+dx+1];
        acc[o][2] += w*t[(dy+1)*4+dx];
        acc[o][3] += w*t[(dy+1)*4+dx+1];
      }
    }
  }
  int wid = threadIdx.x>>6;
  #pragma unroll
  for (int o=0;o<8;o++){
    float m = fmaxf(fmaxf(acc[o][0],acc[o][1]), fmaxf(acc[o][2],acc[o][3]));
    p4[((size_t)b*32 + og*8 + o)*49 + tile] = m;
    float s  = acc[o][0]+acc[o][1]+acc[o][2]+acc[o][3];
    float sq = acc[o][0]*acc[o][0]+acc[o][1]*acc[o][1]+acc[o][2]*acc[o][2]+acc[o][3]*acc[o][3];
    #pragma unroll
    for (int off=32; off; off>>=1){ s += __shfl_down(s,off); sq += __shfl_down(sq,off); }
    if ((threadIdx.x&63)==0){ red[wid][o] = s; red[wid][8+o] = sq; }
  }
  __syncthreads();
  if (threadIdx.x < 16){
    float v = red[0][threadIdx.x]+red[1][threadIdx.x]+red[2][threadIdx.x]+red[3][threadIdx.x];
    int c = og*8 + (threadIdx.x & 7);
    atomicAdd(&st[(threadIdx.x<8)? c : 64+c], v);
  }
}

// ---------------- conv5: 32->64, bn4+relu on read, 8-oc groups, fused stats ----------------
__global__ __launch_bounds__(256) void k_conv5(const float* __restrict__ p4,
                                               const float* __restrict__ w5,
                                               const float* __restrict__ coef,
                                               float* __restrict__ y5,
                                               float* __restrict__ st){
  __shared__ float ws[2304];
  __shared__ float ca[32], cb[32];
  __shared__ float red[4][16];
  int og = blockIdx.x >> 7;                  // 0..7
  int inner = blockIdx.x & 127;
  for (int i=threadIdx.x; i<2304; i+=256) ws[i] = w5[og*2304 + i];
  if (threadIdx.x < 32){ ca[threadIdx.x] = coef[threadIdx.x]; cb[threadIdx.x] = coef[64+threadIdx.x]; }
  __syncthreads();
  int tg = inner*256 + threadIdx.x;
  int b = tg >> 4, tile = tg & 15;
  int ty2 = (tile>>2)*2, tx2 = (tile&3)*2;
  const float* src = p4 + (size_t)b*1568;
  float acc[8][4];
  #pragma unroll
  for (int o=0;o<8;o++){ acc[o][0]=0.f; acc[o][1]=0.f; acc[o][2]=0.f; acc[o][3]=0.f; }
  for (int ci=0; ci<32; ci++){
    float a = ca[ci], bo = cb[ci];
    const float* s2p = src + ci*49;
    float t[16];
    #pragma unroll
    for (int r=0;r<4;r++){
      int iy = ty2-1+r;
      bool vy = (iy>=0 && iy<7);
      #pragma unroll
      for (int c2=0;c2<4;c2++){
        int ix = tx2-1+c2;
        float v = 0.f;
        if (vy && ix>=0 && ix<7) v = fmaxf(s2p[iy*7+ix]*a + bo, 0.f);
        t[r*4+c2] = v;
      }
    }
    #pragma unroll
    for (int o=0;o<8;o++){
      const float* wr = &ws[(o*32+ci)*9];
      #pragma unroll
      for (int k=0;k<9;k++){
        float w = wr[k];
        int dy = k/3, dx = k-dy*3;
        acc[o][0] += w*t[dy*4+dx];
        acc[o][1] += w*t[dy*4+dx+1];
        acc[o][2] += w*t[(dy+1)*4+dx];
        acc[o][3] += w*t[(dy+1)*4+dx+1];
      }
    }
  }
  float v0 = (ty2<7 && tx2<7)?1.f:0.f, v1 = (ty2<7 && tx2+1<7)?1.f:0.f;
  float v2 = (ty2+1<7 && tx2<7)?1.f:0.f, v3 = (ty2+1<7 && tx2+1<7)?1.f:0.f;
  int wid = threadIdx.x>>6;
  #pragma unroll
  for (int o=0;o<8;o++){
    float* dst = y5 + ((size_t)b*64 + og*8 + o)*49;
    if (v0>0.f) dst[ty2*7+tx2]       = acc[o][0];
    if (v1>0.f) dst[ty2*7+tx2+1]     = acc[o][1];
    if (v2>0.f) dst[(ty2+1)*7+tx2]   = acc[o][2];
    if (v3>0.f) dst[(ty2+1)*7+tx2+1] = acc[o][3];
    float s  = v0*acc[o][0]+v1*acc[o][1]+v2*acc[o][2]+v3*acc[o][3];
    float sq = v0*acc[o][0]*acc[o][0]+v1*acc[o][1]*acc[o][1]+v2*acc[o][2]*acc[o][2]+v3*acc[o][3]*acc[o][3];
    #pragma unroll
    for (int off=32; off; off>>=1){ s += __shfl_down(s,off); sq += __shfl_down(sq,off); }
    if ((threadIdx.x&63)==0){ red[wid][o] = s; red[wid][8+o] = sq; }
  }
  __syncthreads();
  if (threadIdx.x < 16){
    float v = red[0][threadIdx.x]+red[1][threadIdx.x]+red[2][threadIdx.x]+red[3][threadIdx.x];
    int c = og*8 + (threadIdx.x & 7);
    atomicAdd(&st[(threadIdx.x<8)? c : 64+c], v);
  }
}

// ---------------- conv6: 64->64, bn5+relu on read, 8-oc groups, fused stats ----------------
__global__ __launch_bounds__(256) void k_conv6(const float* __restrict__ y5,
                                               const float* __restrict__ w6,
                                               const float* __restrict__ coef,
                                               float* __restrict__ y6,
                                               float* __restrict__ st){
  __shared__ float ws[4608];
  __shared__ float ca[64], cb[64];
  __shared__ float red[4][16];
  int og = blockIdx.x >> 7;                  // 0..7
  int inner = blockIdx.x & 127;
  for (int i=threadIdx.x; i<4608; i+=256) ws[i] = w6[og*4608 + i];
  if (threadIdx.x < 64){ ca[threadIdx.x] = coef[threadIdx.x]; cb[threadIdx.x] = coef[64+threadIdx.x]; }
  __syncthreads();
  int tg = inner*256 + threadIdx.x;
  int b = tg >> 4, tile = tg & 15;
  int ty2 = (tile>>2)*2, tx2 = (tile&3)*2;
  const float* src = y5 + (size_t)b*3136;
  float acc[8][4];
  #pragma unroll
  for (int o=0;o<8;o++){ acc[o][0]=0.f; acc[o][1]=0.f; acc[o][2]=0.f; acc[o][3]=0.f; }
  for (int ci=0; ci<64; ci++){
    float a = ca[ci], bo = cb[ci];
    const float* s2p = src + ci*49;
    float t[16];
    #pragma unroll
    for (int r=0;r<4;r++){
      int iy = ty2-1+r;
      bool vy = (iy>=0 && iy<7);
      #pragma unroll
      for (int c2=0;c2<4;c2++){
        int ix = tx2-1+c2;
        float v = 0.f;
        if (vy && ix>=0 && ix<7) v = fmaxf(s2p[iy*7+ix]*a + bo, 0.f);
        t[r*4+c2] = v;
      }
    }
    #pragma unroll
    for (int o=0;o<8;o++){
      const float* wr = &ws[(o*64+ci)*9];
      #pragma unroll
      for (int k=0;k<9;k++){
        float w = wr[k];
        int dy = k/3, dx = k-dy*3;
        acc[o][0] += w*t[dy*4+dx];
        acc[o][1] += w*t[dy*4+dx+1];
        acc[o][2] += w*t[(dy+1)*4+dx];
        acc[o][3] += w*t[(dy+1)*4+dx+1];
      }
    }
  }
  float v0 = (ty2<7 && tx2<7)?1.f:0.f, v1 = (ty2<7 && tx2+1<7)?1.f:0.f;
  float v2 = (ty2+1<7 && tx2<7)?1.f:0.f, v3 = (ty2+1<7 && tx2+1<7)?1.f:0.f;
  int wid = threadIdx.x>>6;
  #pragma unroll
  for (int o=0;o<8;o++){
    float* dst = y6 + ((size_t)b*64 + og*8 + o)*49;
    if (v0>0.f) dst[ty2*7+tx2]       = acc[o][0];
    if (v1>0.f) dst[ty2*7+tx2+1]     = acc[o][1];
    if (v2>0.f) dst[(ty2+1)*7+tx2]   = acc[o][2];
    if (v3>0.f) dst[(ty2+1)*7+tx2+1] = acc[o][3];
    float s  = v0*acc[o][0]+v1*acc[o][1]+v2*acc[o][2]+v3*acc[o][3];
    float sq = v0*acc[o][0]*acc[o][0]+v1*acc[o][1]*acc[o][1]+v2*acc[o][2]*acc[o][2]+v3*acc[o][3]*acc[o][3];
    #pragma unroll
    for (int off=32; off; off>>=1){ s += __shfl_down(s,off); sq += __shfl_down(sq,off); }
    if ((threadIdx.x&63)==0){ red[wid][o] = s; red[wid][8+o] = sq; }
  }
  __syncthreads();
  if (threadIdx.x < 16){
    float v = red[0][threadIdx.x]+red[1][threadIdx.x]+red[2][threadIdx.x]+red[3][threadIdx.x];
    int c = og*8 + (threadIdx.x & 7);
    atomicAdd(&st[(threadIdx.x<8)? c : 64+c], v);
  }
}

// ---------------- bn6+relu + 2x2 pool pad 1 (7 -> 4) ----------------
__global__ __launch_bounds__(256) void k_pool6(const float* __restrict__ y,
                                               const float* __restrict__ coef,
                                               float* __restrict__ p){
  int idx = blockIdx.x*256 + threadIdx.x;       // NB*64*16 exact
  int xo = idx & 3; int t1 = idx >> 2;
  int yo = t1 & 3;  int t2 = t1 >> 2;
  int c = t2 & 63;  int b = t2 >> 6;
  float a = coef[c], bo = coef[64+c];
  const float* src = y + ((size_t)b*64 + c)*49;
  float m = -1e30f;
  #pragma unroll
  for (int dy=0;dy<2;dy++){
    int iy = yo*2 - 1 + dy;
    if (iy < 0 || iy >= 7) continue;
    #pragma unroll
    for (int dx=0;dx<2;dx++){
      int ix = xo*2 - 1 + dx;
      if (ix < 0 || ix >= 7) continue;
      m = fmaxf(m, src[iy*7+ix]*a + bo);
    }
  }
  p[idx] = fmaxf(m, 0.f);
}

// ---------------- conv7: lane=(batch,pos), wave-uniform weights (s_load), LDS-padded x ----------------
__global__ __launch_bounds__(256) void k_conv7(const float* __restrict__ p6,
                                               const float* __restrict__ w7,
                                               const float* __restrict__ bias,
                                               const float* __restrict__ nmsa,
                                               float* __restrict__ out){
  __shared__ float xs[8*2056];               // per-b stride 2056 (bank skew), rows 4 x 8 padded cols
  __shared__ float vals[8][10][25];
  int b0 = blockIdx.x*8;                     // grid 256
  for (int i=threadIdx.x; i<8*2056; i+=256) xs[i] = 0.f;
  __syncthreads();
  for (int i=threadIdx.x; i<8192; i+=256){
    int bl = i>>10, rem = i&1023;
    int ci = rem>>4, r = (rem>>2)&3, c = rem&3;
    xs[bl*2056 + ci*32 + r*8 + c + 2] = p6[(size_t)(b0+bl)*1024 + rem];
  }
  __syncthreads();
  int t = threadIdx.x;
  int bl = t/25, pos = t - bl*25;
  if (bl < 8){
    int py = pos/5, px = pos - py*5;
    float acc[10];
    #pragma unroll
    for (int o=0;o<10;o++) acc[o] = 0.f;
    for (int ci=0; ci<64; ci++){
      float xt[16];
      #pragma unroll
      for (int ky=0; ky<4; ky++){
        int r = py + ky - 2;
        bool vr = (r>=0 && r<4);
        int rr = vr ? r : 0;
        const float* row = &xs[bl*2056 + ci*32 + rr*8 + px];
        #pragma unroll
        for (int kx=0;kx<4;kx++) xt[ky*4+kx] = vr ? row[kx] : 0.f;
      }
      #pragma unroll
      for (int o=0;o<10;o++){
        const float* wr = w7 + o*1024 + ci*16;   // wave-uniform -> scalar loads
        #pragma unroll
        for (int k=0;k<16;k++) acc[o] += wr[k]*xt[k];
      }
    }
    #pragma unroll
    for (int o=0;o<10;o++) vals[bl][o][pos] = acc[o];
  }
  __syncthreads();
  if (t < 80){
    int b2 = t/10, o = t - b2*10;
    float m = vals[b2][o][0];
    #pragma unroll
    for (int p=1;p<25;p++) m = fmaxf(m, vals[b2][o][p]);
    out[(b0+b2)*10 + o] = m + bias[o];
  }
  if (blockIdx.x == 0 && t == 255) out[20480] = nmsa[0] * (1.f/12845056.f);
}

extern "C" void kernel_launch(void* const* d_in, const int* in_sizes, int n_in,
                              void* d_out, int out_size, void* d_ws, size_t ws_size,
                              hipStream_t stream){
  const float* x  = (const float*)d_in[0];
  const float* w1 = (const float*)d_in[1];
  const float* w2 = (const float*)d_in[2];
  const float* w3 = (const float*)d_in[3];
  const float* w4 = (const float*)d_in[4];
  const float* w5 = (const float*)d_in[5];
  const float* w6 = (const float*)d_in[6];
  const float* w7 = (const float*)d_in[7];
  const float* g1 = (const float*)d_in[8];
  const float* b1 = (const float*)d_in[9];
  const float* g2 = (const float*)d_in[10];
  const float* b2 = (const float*)d_in[11];
  const float* g3 = (const float*)d_in[12];
  const float* b3 = (const float*)d_in[13];
  const float* g4 = (const float*)d_in[14];
  const float* b4 = (const float*)d_in[15];
  const float* g5 = (const float*)d_in[16];
  const float* b5 = (const float*)d_in[17];
  const float* g6 = (const float*)d_in[18];
  const float* b6 = (const float*)d_in[19];
  const float* b7 = (const float*)d_in[20];
  float* out = (float*)d_out;
  float* W = (float*)d_ws;

  // arena (floats), all disjoint:
  float* p2 = W;                       //  6,422,528  (2048*16*196)
  float* y3 = W + 6422528;             // 12,845,056  (2048*32*196)
  float* p4 = W + 19267584;            //  3,211,264  (2048*32*49)
  float* y5 = W + 22478848;            //  6,422,528  (2048*64*49)
  float* y6 = W + 28901376;            //  6,422,528
  float* p6 = W + 35323904;            //  2,097,152  (2048*64*16)
  float* st = W + 37421056;            //  2048: sums[6*128] | coefs at +768 | nms at +1536

  float* cf = st + 768;
  float* nmsa = st + 1536;

  k_zero<<<8,256,0,stream>>>(st);

  k_stats1<<<512,256,0,stream>>>(x, w1, st + 0*128);
  k_fin<<<1,64,0,stream>>>(st + 0*128, g1, b1, cf + 0*128, 16, 1, 1.f/1605632.f);

  k_conv2<<<1568,256,0,stream>>>(x, w1, w2, cf + 0*128, p2, st + 1*128);
  k_fin<<<1,64,0,stream>>>(st + 1*128, g2, b2, cf + 1*128, 16, 1, 1.f/1605632.f);

  k_conv3<<<784,256,0,stream>>>(p2, w3, cf + 1*128, y3, st + 2*128);
  k_fin<<<1,64,0,stream>>>(st + 2*128, g3, b3, cf + 2*128, 32, 3, 1.f/401408.f);
  k_nms<<<6272,256,0,stream>>>(y3, cf + 2*128, nmsa);

  k_conv4<<<1568,256,0,stream>>>(y3, w4, cf + 2*128, p4, st + 3*128);
  k_fin<<<1,64,0,stream>>>(st + 3*128, g4, b4, cf + 3*128, 32, 31, 1.f/401408.f);

  k_conv5<<<1024,256,0,stream>>>(p4, w5, cf + 3*128, y5, st + 4*128);
  k_fin<<<1,64,0,stream>>>(st + 4*128, g5, b5, cf + 4*128, 64, 63, 1.f/100352.f);

  k_conv6<<<1024,256,0,stream>>>(y5, w6, cf + 4*128, y6, st + 5*128);
  k_fin<<<1,64,0,stream>>>(st + 5*128, g6, b6, cf + 5*128, 64, 63, 1.f/100352.f);
  k_pool6<<<8192,256,0,stream>>>(y6, cf + 5*128, p6);

  k_conv7<<<256,256,0,stream>>>(p6, w7, b7, nmsa, out);
}

// Round 5
// 1066.722 us; speedup vs baseline: 2.0713x; 1.1314x over previous
//
#include <hip/hip_runtime.h>

static constexpr int NB = 2048;
static constexpr float SENT = -1e30f;

// rotated-3x3 tap permutation: weight tap k of rotation r lands at patch position DST[r][k]
static constexpr int DST[8][9] = {
  {8,7,6,5,4,3,2,1,0},
  {5,8,7,2,4,6,1,0,3},
  {2,5,8,1,4,7,0,3,6},
  {1,2,5,0,4,8,3,6,7},
  {0,1,2,3,4,5,6,7,8},
  {3,0,1,6,4,2,7,8,5},
  {6,3,0,7,4,1,8,5,2},
  {7,6,3,8,4,0,5,2,1},
};

// border cell index (16x16 plane) for border id t<60
__device__ __forceinline__ int border_cell(int t){
  if (t<16) return t;                 // row 0
  if (t<32) return 240 + (t-16);      // row 15
  if (t<46) return (t-31)*16;         // col 0, rows 1..14
  return (t-45)*16 + 15;              // col 15, rows 1..14
}

// ---------------- zero stats region ----------------
__global__ __launch_bounds__(256) void k_zero(float* st){
  int i = blockIdx.x*256 + threadIdx.x;
  if (i < 2048) st[i] = 0.f;
}

// ---------------- pad x into 32x32 planes (zero border, interior at (2,2)) ----------------
__global__ __launch_bounds__(256) void k_xpad(const float* __restrict__ x, float* __restrict__ xp){
  int i = blockIdx.x*256 + threadIdx.x;       // 2048*1024
  int b = i>>10, rem = i&1023;
  int r = rem>>5, c = rem&31;
  int iy = r-2, ix = c-2;
  xp[i] = (iy>=0 && iy<28 && ix>=0 && ix<28) ? x[(size_t)b*784 + iy*28 + ix] : 0.f;
}

// ---------------- transpose w5,w6 to [ci*9+k][oc] ----------------
__global__ __launch_bounds__(256) void k_wt(const float* __restrict__ w5, const float* __restrict__ w6,
                                            float* __restrict__ wT5, float* __restrict__ wT6){
  int i = blockIdx.x*256 + threadIdx.x;
  if (i < 32*9*64){
    int ck = i>>6, oc = i&63; int ci = ck/9, k = ck - ci*9;
    wT5[ck*64+oc] = w5[(oc*32+ci)*9 + k];
  } else if (i < 32*9*64 + 64*9*64){
    int j = i - 32*9*64;
    int ck = j>>6, oc = j&63; int ci = ck/9, k = ck - ci*9;
    wT6[ck*64+oc] = w6[(oc*64+ci)*9 + k];
  }
}

// ---------------- stats of y1 = rotconv1(x), y1 never materialized ----------------
__global__ __launch_bounds__(256) void k_stats1(const float* __restrict__ x,
                                                const float* __restrict__ w1,
                                                float* __restrict__ st){
  __shared__ float wp[192];
  __shared__ float red[4][32];
  for (int i=threadIdx.x; i<144; i+=256){
    int rot = i/18, rem = i-rot*18, u = rem/9, k = rem-u*9;
    wp[(rot*2+u)*12 + DST[rot][k]] = w1[u*9+k];
  }
  __syncthreads();
  float s[16], s2[16];
  #pragma unroll
  for (int o=0;o<16;o++){ s[o]=0.f; s2[o]=0.f; }
  for (int idx = blockIdx.x*256 + threadIdx.x; idx < NB*784; idx += 512*256){
    int b = idx/784, pix = idx-b*784;
    int py = pix/28, px = pix-py*28;
    const float* xb = x + (size_t)b*784;
    float tap[9];
    #pragma unroll
    for (int d=0; d<9; d++){
      int dy = d/3-1, dx = d%3-1;
      int yy = py+dy, xx = px+dx;
      tap[d] = (yy>=0 && yy<28 && xx>=0 && xx<28) ? xb[yy*28+xx] : 0.f;
    }
    #pragma unroll
    for (int ci=0; ci<16; ci++){
      float y = 0.f;
      #pragma unroll
      for (int d=0; d<9; d++) y += wp[ci*12+d]*tap[d];
      s[ci] += y; s2[ci] += y*y;
    }
  }
  int wid = threadIdx.x>>6;
  #pragma unroll
  for (int o=0;o<16;o++){
    float a = s[o], b2 = s2[o];
    #pragma unroll
    for (int off=32; off; off>>=1){ a += __shfl_down(a,off); b2 += __shfl_down(b2,off); }
    if ((threadIdx.x&63)==0){ red[wid][o] = a; red[wid][16+o] = b2; }
  }
  __syncthreads();
  if (threadIdx.x < 32){
    float v = red[0][threadIdx.x]+red[1][threadIdx.x]+red[2][threadIdx.x]+red[3][threadIdx.x];
    int c = threadIdx.x & 15;
    atomicAdd(&st[(threadIdx.x<16)? c : 64+c], v);
  }
}

// ---------------- BN finalize ----------------
__global__ void k_fin(const float* __restrict__ st, const float* __restrict__ g,
                      const float* __restrict__ be, float* __restrict__ coef,
                      int C, int gmask, float invN){
  int c = threadIdx.x;
  if (c >= C) return;
  float mu  = st[c]*invN;
  float var = st[64+c]*invN - mu*mu;
  float a = g[c & gmask] * rsqrtf(var + 1e-5f);
  coef[c]    = a;
  coef[64+c] = be[c & gmask] - mu*a;
}

// ---------------- conv2: recompute y1 from xpad, rot-conv 16->16, stats + raw pool -> padded p2 ----------------
__global__ __launch_bounds__(256) void k_conv2(const float* __restrict__ xp,
                                               const float* __restrict__ w1,
                                               const float* __restrict__ w2,
                                               const float* __restrict__ coef,
                                               float* __restrict__ p2p,
                                               float* __restrict__ st){
  __shared__ float wp[192];
  __shared__ float ws[384];
  __shared__ float ca[16], cb[16];
  __shared__ float red[4][32];
  for (int i=threadIdx.x; i<144; i+=256){
    int rot = i/18, rem = i-rot*18, u = rem/9, k = rem-u*9;
    wp[(rot*2+u)*12 + DST[rot][k]] = w1[u*9+k];
  }
  for (int i=threadIdx.x; i<288; i+=256){
    int f = i/9, k = i-f*9;
    ws[f*12+k] = w2[i];
  }
  if (threadIdx.x < 16){ ca[threadIdx.x] = coef[threadIdx.x]; cb[threadIdx.x] = coef[64+threadIdx.x]; }
  __syncthreads();
  int tg = blockIdx.x*256 + threadIdx.x;    // 2048*196 (1568 blocks)
  int b = tg / 196, tile = tg - b*196;
  int ty2 = (tile/14)*2, tx2 = (tile%14)*2;
  // 6x6 x patch, branch-free from padded x
  const float* xb = xp + (size_t)b*1024 + ty2*32 + tx2;
  float xv[36];
  #pragma unroll
  for (int r=0;r<6;r++){
    float2 A = *(const float2*)(xb + r*32);
    float2 B = *(const float2*)(xb + r*32 + 2);
    float2 C = *(const float2*)(xb + r*32 + 4);
    xv[r*6+0]=A.x; xv[r*6+1]=A.y; xv[r*6+2]=B.x; xv[r*6+3]=B.y; xv[r*6+4]=C.x; xv[r*6+5]=C.y;
  }
  // validity of y1 4x4 patch (conv2's own zero padding)
  float vm[16];
  #pragma unroll
  for (int r=0;r<4;r++){
    int iy = ty2-1+r;
    #pragma unroll
    for (int c=0;c<4;c++){
      int ix = tx2-1+c;
      vm[r*4+c] = (iy>=0 && iy<28 && ix>=0 && ix<28) ? 1.f : 0.f;
    }
  }
  float acc[16][4];
  #pragma unroll
  for (int o=0;o<16;o++){ acc[o][0]=0.f; acc[o][1]=0.f; acc[o][2]=0.f; acc[o][3]=0.f; }
  for (int ci=0; ci<16; ci++){
    float a = ca[ci], bo = cb[ci];
    float wv1[9];
    #pragma unroll
    for (int d=0; d<9; d++) wv1[d] = wp[ci*12+d];
    float t[16];
    #pragma unroll
    for (int r=0;r<4;r++){
      #pragma unroll
      for (int c=0;c<4;c++){
        float y = 0.f;
        #pragma unroll
        for (int d=0; d<9; d++){
          int dy = d/3, dx = d-dy*3;
          y += wv1[d]*xv[(r+dy)*6 + (c+dx)];
        }
        t[r*4+c] = vm[r*4+c]*fmaxf(a*y + bo, 0.f);
      }
    }
    int bb = ci>>1, ui = ci&1;
    #pragma unroll
    for (int rot=0; rot<8; rot++){
      int wc = (((bb - rot) & 7)<<1) | ui;
      #pragma unroll
      for (int u=0; u<2; u++){
        const float* wr = &ws[(u*16+wc)*12];
        float4 wA = *(const float4*)wr;
        float4 wB = *(const float4*)(wr+4);
        float w8 = wr[8];
        float wv[9] = {wA.x,wA.y,wA.z,wA.w,wB.x,wB.y,wB.z,wB.w,w8};
        #pragma unroll
        for (int k=0;k<9;k++){
          int d = DST[rot][k];
          int dy = d/3, dx = d-dy*3;
          float w = wv[k];
          acc[rot*2+u][0] += w*t[dy*4+dx];
          acc[rot*2+u][1] += w*t[dy*4+dx+1];
          acc[rot*2+u][2] += w*t[(dy+1)*4+dx];
          acc[rot*2+u][3] += w*t[(dy+1)*4+dx+1];
        }
      }
    }
  }
  // epilogue: raw 2x2 pool into padded plane + sentinel border + stats
  int py = tile/14, px = tile%14;
  int cell = (py+1)*16 + px + 1;
  int wid = threadIdx.x>>6;
  #pragma unroll
  for (int o=0;o<16;o++){
    float m = fmaxf(fmaxf(acc[o][0],acc[o][1]), fmaxf(acc[o][2],acc[o][3]));
    p2p[((size_t)b*16+o)*256 + cell] = m;
    float s  = acc[o][0]+acc[o][1]+acc[o][2]+acc[o][3];
    float s2 = acc[o][0]*acc[o][0]+acc[o][1]*acc[o][1]+acc[o][2]*acc[o][2]+acc[o][3]*acc[o][3];
    #pragma unroll
    for (int off=32; off; off>>=1){ s += __shfl_down(s,off); s2 += __shfl_down(s2,off); }
    if ((threadIdx.x&63)==0){ red[wid][o] = s; red[wid][16+o] = s2; }
  }
  if (tile < 60){
    int bc = border_cell(tile);
    #pragma unroll
    for (int o=0;o<16;o++) p2p[((size_t)b*16+o)*256 + bc] = SENT;
  }
  __syncthreads();
  if (threadIdx.x < 32){
    float v = red[0][threadIdx.x]+red[1][threadIdx.x]+red[2][threadIdx.x]+red[3][threadIdx.x];
    int c = threadIdx.x & 15;
    atomicAdd(&st[(threadIdx.x<16)? c : 64+c], v);
  }
}

// ---------------- conv3: 16->32 rotated, bn2+relu on read (sentinel-safe), stats, padded y3 out ----------------
__global__ __launch_bounds__(256) void k_conv3(const float* __restrict__ p2p,
                                               const float* __restrict__ w3,
                                               const float* __restrict__ coef,
                                               float* __restrict__ y3p,
                                               float* __restrict__ st){
  __shared__ float ws[384];
  __shared__ float ca[16], cb[16];
  __shared__ float red[4][32];
  int uh = blockIdx.x / 392;
  int inner = blockIdx.x - uh*392;
  for (int i=threadIdx.x; i<288; i+=256){
    int f = i/9, k = i-f*9;
    ws[f*12+k] = w3[uh*288 + i];
  }
  if (threadIdx.x < 16){ ca[threadIdx.x] = coef[threadIdx.x]; cb[threadIdx.x] = coef[64+threadIdx.x]; }
  __syncthreads();
  int tg = inner*256 + threadIdx.x;
  int b = tg / 49, tile = tg - b*49;
  int ty2 = (tile/7)*2, tx2 = (tile%7)*2;
  const float* src0 = p2p + (size_t)b*4096 + ty2*16 + tx2;
  float acc[16][4];
  #pragma unroll
  for (int o=0;o<16;o++){ acc[o][0]=0.f; acc[o][1]=0.f; acc[o][2]=0.f; acc[o][3]=0.f; }
  for (int ci=0; ci<16; ci++){
    float a = ca[ci], bo = cb[ci];
    const float* s2p = src0 + ci*256;
    float t[16];
    #pragma unroll
    for (int r=0;r<4;r++){
      float2 A = *(const float2*)(s2p + r*16);
      float2 B = *(const float2*)(s2p + r*16 + 2);
      t[r*4+0] = fmaxf(A.x*a+bo, 0.f);
      t[r*4+1] = fmaxf(A.y*a+bo, 0.f);
      t[r*4+2] = fmaxf(B.x*a+bo, 0.f);
      t[r*4+3] = fmaxf(B.y*a+bo, 0.f);
    }
    int bb = ci>>1, ui = ci&1;
    #pragma unroll
    for (int rot=0; rot<8; rot++){
      int wc = (((bb - rot) & 7)<<1) | ui;
      #pragma unroll
      for (int ul=0; ul<2; ul++){
        const float* wr = &ws[(ul*16+wc)*12];
        float4 wA = *(const float4*)wr;
        float4 wB = *(const float4*)(wr+4);
        float w8 = wr[8];
        float wv[9] = {wA.x,wA.y,wA.z,wA.w,wB.x,wB.y,wB.z,wB.w,w8};
        #pragma unroll
        for (int k=0;k<9;k++){
          int d = DST[rot][k];
          int dy = d/3, dx = d-dy*3;
          float w = wv[k];
          acc[rot*2+ul][0] += w*t[dy*4+dx];
          acc[rot*2+ul][1] += w*t[dy*4+dx+1];
          acc[rot*2+ul][2] += w*t[(dy+1)*4+dx];
          acc[rot*2+ul][3] += w*t[(dy+1)*4+dx+1];
        }
      }
    }
  }
  // write interior (padded plane), sentinel border, stats
  float* ob = y3p + (size_t)b*8192 + (ty2+1)*16 + (tx2+1);
  int wid = threadIdx.x>>6;
  #pragma unroll
  for (int rot=0;rot<8;rot++){
    #pragma unroll
    for (int ul=0;ul<2;ul++){
      int j = rot*2+ul;
      float* dst = ob + (rot*4 + uh*2 + ul)*256;
      dst[0]  = acc[j][0]; dst[1]  = acc[j][1];
      dst[16] = acc[j][2]; dst[17] = acc[j][3];
      float s  = acc[j][0]+acc[j][1]+acc[j][2]+acc[j][3];
      float sq = acc[j][0]*acc[j][0]+acc[j][1]*acc[j][1]+acc[j][2]*acc[j][2]+acc[j][3]*acc[j][3];
      #pragma unroll
      for (int off=32; off; off>>=1){ s += __shfl_down(s,off); sq += __shfl_down(sq,off); }
      if ((threadIdx.x&63)==0){ red[wid][j] = s; red[wid][16+j] = sq; }
    }
  }
  // border fill: tile only spans 0..48 here, so cover 60 cells with a strided loop
  for (int t2 = tile; t2 < 60; t2 += 49){
    int bc = border_cell(t2);
    #pragma unroll
    for (int rot=0;rot<8;rot++){
      #pragma unroll
      for (int ul=0;ul<2;ul++)
        y3p[((size_t)b*32 + rot*4 + uh*2 + ul)*256 + bc] = SENT;
    }
  }
  __syncthreads();
  if (threadIdx.x < 32){
    float v = red[0][threadIdx.x]+red[1][threadIdx.x]+red[2][threadIdx.x]+red[3][threadIdx.x];
    int j = threadIdx.x & 15;
    int c = (j>>1)*4 + uh*2 + (j&1);
    atomicAdd(&st[(threadIdx.x<16)? c : 64+c], v);
  }
}

// ---------------- nms (padded y3) ----------------
__global__ __launch_bounds__(256) void k_nms(const float* __restrict__ y3p,
                                             const float* __restrict__ coef,
                                             float* __restrict__ accum){
  int idx = blockIdx.x*256 + threadIdx.x;       // NB*4*196 exact
  int hw = idx % 196; int t1 = idx / 196;
  int c4 = t1 & 3;    int b = t1 >> 2;
  int py = hw/14, px = hw%14;
  const float* base = y3p + ((size_t)b*32 + c4*8)*256 + (py+1)*16 + (px+1);
  float v[8]; float vmax = -1e30f;
  #pragma unroll
  for (int r=0;r<8;r++){
    int c = c4*8 + r;
    float z = fmaxf(base[r*256]*coef[c] + coef[64+c], 0.f);
    v[r] = z;
    vmax = fmaxf(vmax, z);
  }
  float local = 0.f;
  #pragma unroll
  for (int r=0;r<8;r++) local += (v[r] != vmax) ? v[r] : 0.f;
  #pragma unroll
  for (int off=32; off; off>>=1) local += __shfl_down(local, off);
  __shared__ float sh[4];
  if ((threadIdx.x & 63) == 0) sh[threadIdx.x>>6] = local;
  __syncthreads();
  if (threadIdx.x == 0) atomicAdd(accum, sh[0]+sh[1]+sh[2]+sh[3]);
}

// ---------------- conv4: 32->32, bn3+relu on read, 16-oc halves, stats + raw pool (stride-52 planes) ----------------
__global__ __launch_bounds__(256) void k_conv4(const float* __restrict__ y3p,
                                               const float* __restrict__ w4,
                                               const float* __restrict__ coef,
                                               float* __restrict__ p4,
                                               float* __restrict__ st){
  __shared__ float ws[6144];                 // 16 oc x 32 ci, stride 12
  __shared__ float ca[32], cb[32];
  __shared__ float red[4][32];
  int oh = blockIdx.x / 392;                 // 0..1
  int inner = blockIdx.x - oh*392;
  for (int i=threadIdx.x; i<4608; i+=256){
    int f = i/9, k = i-f*9;
    ws[f*12+k] = w4[oh*4608 + i];
  }
  if (threadIdx.x < 32){ ca[threadIdx.x] = coef[threadIdx.x]; cb[threadIdx.x] = coef[64+threadIdx.x]; }
  __syncthreads();
  int tg = inner*256 + threadIdx.x;
  int b = tg / 49, tile = tg - b*49;
  int ty2 = (tile/7)*2, tx2 = (tile%7)*2;
  const float* src0 = y3p + (size_t)b*8192 + ty2*16 + tx2;
  float acc[16][4];
  #pragma unroll
  for (int o=0;o<16;o++){ acc[o][0]=0.f; acc[o][1]=0.f; acc[o][2]=0.f; acc[o][3]=0.f; }
  #pragma unroll 2
  for (int ci=0; ci<32; ci++){
    float a = ca[ci], bo = cb[ci];
    const float* s2p = src0 + ci*256;
    float t[16];
    #pragma unroll
    for (int r=0;r<4;r++){
      float2 A = *(const float2*)(s2p + r*16);
      float2 B = *(const float2*)(s2p + r*16 + 2);
      t[r*4+0] = fmaxf(A.x*a+bo, 0.f);
      t[r*4+1] = fmaxf(A.y*a+bo, 0.f);
      t[r*4+2] = fmaxf(B.x*a+bo, 0.f);
      t[r*4+3] = fmaxf(B.y*a+bo, 0.f);
    }
    #pragma unroll
    for (int o=0;o<16;o++){
      const float* wr = &ws[(o*32+ci)*12];
      float4 wA = *(const float4*)wr;
      float4 wB = *(const float4*)(wr+4);
      float w8 = wr[8];
      float wv[9] = {wA.x,wA.y,wA.z,wA.w,wB.x,wB.y,wB.z,wB.w,w8};
      #pragma unroll
      for (int k=0;k<9;k++){
        float w = wv[k];
        int dy = k/3, dx = k-dy*3;
        acc[o][0] += w*t[dy*4+dx];
        acc[o][1] += w*t[dy*4+dx+1];
        acc[o][2] += w*t[(dy+1)*4+dx];
        acc[o][3] += w*t[(dy+1)*4+dx+1];
      }
    }
  }
  int wid = threadIdx.x>>6;
  #pragma unroll
  for (int o=0;o<16;o++){
    float m = fmaxf(fmaxf(acc[o][0],acc[o][1]), fmaxf(acc[o][2],acc[o][3]));
    p4[((size_t)b*32 + oh*16 + o)*52 + tile] = m;
    float s  = acc[o][0]+acc[o][1]+acc[o][2]+acc[o][3];
    float sq = acc[o][0]*acc[o][0]+acc[o][1]*acc[o][1]+acc[o][2]*acc[o][2]+acc[o][3]*acc[o][3];
    #pragma unroll
    for (int off=32; off; off>>=1){ s += __shfl_down(s,off); sq += __shfl_down(sq,off); }
    if ((threadIdx.x&63)==0){ red[wid][o] = s; red[wid][16+o] = sq; }
  }
  __syncthreads();
  if (threadIdx.x < 32){
    float v = red[0][threadIdx.x]+red[1][threadIdx.x]+red[2][threadIdx.x]+red[3][threadIdx.x];
    int c = oh*16 + (threadIdx.x & 15);
    atomicAdd(&st[(threadIdx.x<16)? c : 64+c], v);
  }
}

// ---------------- conv5: 32->64, wave=batch lane=oc; bn4+relu on read; stats; stride-52 out ----------------
__global__ __launch_bounds__(256) void k_conv5(const float* __restrict__ p4,
                                               const float* __restrict__ wT5,
                                               const float* __restrict__ coef,
                                               float* __restrict__ y5,
                                               float* __restrict__ st){
  __shared__ float ca[32], cb[32];
  __shared__ float red[4][128];
  if (threadIdx.x < 32){ ca[threadIdx.x] = coef[threadIdx.x]; cb[threadIdx.x] = coef[64+threadIdx.x]; }
  __syncthreads();
  int wid = threadIdx.x>>6;
  int lane = threadIdx.x&63;
  int b = blockIdx.x*4 + wid;
  const float* src = p4 + (size_t)b*32*52;
  float acc[49];
  #pragma unroll
  for (int p=0;p<49;p++) acc[p] = 0.f;
  for (int ci=0; ci<32; ci++){
    float a = ca[ci], bo = cb[ci];
    const float* pl = src + ci*52;
    float raw[52] __attribute__((aligned(16)));
    #pragma unroll
    for (int j=0;j<12;j++) *(float4*)&raw[j*4] = *(const float4*)(pl + j*4);
    raw[48] = pl[48];
    float wv[9];
    #pragma unroll
    for (int k=0;k<9;k++) wv[k] = wT5[(ci*9+k)*64 + lane];
    #pragma unroll
    for (int p=0;p<49;p++){
      float v = fmaxf(raw[p]*a + bo, 0.f);
      int iy = p/7, ix = p%7;
      #pragma unroll
      for (int k=0;k<9;k++){
        int dy = k/3, dx = k-dy*3;
        int oy = iy-dy+1, ox = ix-dx+1;
        if (oy>=0 && oy<7 && ox>=0 && ox<7) acc[oy*7+ox] += wv[k]*v;
      }
    }
  }
  float* dst = y5 + ((size_t)b*64 + lane)*52;
  float s=0.f, sq=0.f;
  #pragma unroll
  for (int p=0;p<49;p++){ dst[p] = acc[p]; s += acc[p]; sq += acc[p]*acc[p]; }
  red[wid][lane] = s; red[wid][64+lane] = sq;
  __syncthreads();
  if (threadIdx.x < 128){
    float v = red[0][threadIdx.x]+red[1][threadIdx.x]+red[2][threadIdx.x]+red[3][threadIdx.x];
    int c = threadIdx.x & 63;
    atomicAdd(&st[(threadIdx.x<64)? c : 64+c], v);
  }
}

// ---------------- conv6: 64->64, wave=batch lane=oc; bn5+relu on read; stats; 49-stride out ----------------
__global__ __launch_bounds__(256) void k_conv6(const float* __restrict__ y5,
                                               const float* __restrict__ wT6,
                                               const float* __restrict__ coef,
                                               float* __restrict__ y6,
                                               float* __restrict__ st){
  __shared__ float ca[64], cb[64];
  __shared__ float red[4][128];
  if (threadIdx.x < 64){ ca[threadIdx.x] = coef[threadIdx.x]; cb[threadIdx.x] = coef[64+threadIdx.x]; }
  __syncthreads();
  int wid = threadIdx.x>>6;
  int lane = threadIdx.x&63;
  int b = blockIdx.x*4 + wid;
  const float* src = y5 + (size_t)b*64*52;
  float acc[49];
  #pragma unroll
  for (int p=0;p<49;p++) acc[p] = 0.f;
  for (int ci=0; ci<64; ci++){
    float a = ca[ci], bo = cb[ci];
    const float* pl = src + ci*52;
    float raw[52] __attribute__((aligned(16)));
    #pragma unroll
    for (int j=0;j<12;j++) *(float4*)&raw[j*4] = *(const float4*)(pl + j*4);
    raw[48] = pl[48];
    float wv[9];
    #pragma unroll
    for (int k=0;k<9;k++) wv[k] = wT6[(ci*9+k)*64 + lane];
    #pragma unroll
    for (int p=0;p<49;p++){
      float v = fmaxf(raw[p]*a + bo, 0.f);
      int iy = p/7, ix = p%7;
      #pragma unroll
      for (int k=0;k<9;k++){
        int dy = k/3, dx = k-dy*3;
        int oy = iy-dy+1, ox = ix-dx+1;
        if (oy>=0 && oy<7 && ox>=0 && ox<7) acc[oy*7+ox] += wv[k]*v;
      }
    }
  }
  float* dst = y6 + ((size_t)b*64 + lane)*49;
  float s=0.f, sq=0.f;
  #pragma unroll
  for (int p=0;p<49;p++){ dst[p] = acc[p]; s += acc[p]; sq += acc[p]*acc[p]; }
  red[wid][lane] = s; red[wid][64+lane] = sq;
  __syncthreads();
  if (threadIdx.x < 128){
    float v = red[0][threadIdx.x]+red[1][threadIdx.x]+red[2][threadIdx.x]+red[3][threadIdx.x];
    int c = threadIdx.x & 63;
    atomicAdd(&st[(threadIdx.x<64)? c : 64+c], v);
  }
}

// ---------------- bn6+relu + 2x2 pool pad 1 (7 -> 4) ----------------
__global__ __launch_bounds__(256) void k_pool6(const float* __restrict__ y,
                                               const float* __restrict__ coef,
                                               float* __restrict__ p){
  int idx = blockIdx.x*256 + threadIdx.x;       // NB*64*16 exact
  int xo = idx & 3; int t1 = idx >> 2;
  int yo = t1 & 3;  int t2 = t1 >> 2;
  int c = t2 & 63;  int b = t2 >> 6;
  float a = coef[c], bo = coef[64+c];
  const float* src = y + ((size_t)b*64 + c)*49;
  float m = -1e30f;
  #pragma unroll
  for (int dy=0;dy<2;dy++){
    int iy = yo*2 - 1 + dy;
    if (iy < 0 || iy >= 7) continue;
    #pragma unroll
    for (int dx=0;dx<2;dx++){
      int ix = xo*2 - 1 + dx;
      if (ix < 0 || ix >= 7) continue;
      m = fmaxf(m, src[iy*7+ix]*a + bo);
    }
  }
  p[idx] = fmaxf(m, 0.f);
}

// ---------------- conv7 ----------------
__global__ __launch_bounds__(256) void k_conv7(const float* __restrict__ p6,
                                               const float* __restrict__ w7,
                                               const float* __restrict__ bias,
                                               const float* __restrict__ nmsa,
                                               float* __restrict__ out){
  __shared__ float xs[8*2056];
  __shared__ float vals[8][10][25];
  int b0 = blockIdx.x*8;                     // grid 256
  for (int i=threadIdx.x; i<8*2056; i+=256) xs[i] = 0.f;
  __syncthreads();
  for (int i=threadIdx.x; i<8192; i+=256){
    int bl = i>>10, rem = i&1023;
    int ci = rem>>4, r = (rem>>2)&3, c = rem&3;
    xs[bl*2056 + ci*32 + r*8 + c + 2] = p6[(size_t)(b0+bl)*1024 + rem];
  }
  __syncthreads();
  int t = threadIdx.x;
  int bl = t/25, pos = t - bl*25;
  if (bl < 8){
    int py = pos/5, px = pos - py*5;
    float acc[10];
    #pragma unroll
    for (int o=0;o<10;o++) acc[o] = 0.f;
    for (int ci=0; ci<64; ci++){
      float xt[16];
      #pragma unroll
      for (int ky=0; ky<4; ky++){
        int r = py + ky - 2;
        bool vr = (r>=0 && r<4);
        int rr = vr ? r : 0;
        const float* row = &xs[bl*2056 + ci*32 + rr*8 + px];
        #pragma unroll
        for (int kx=0;kx<4;kx++) xt[ky*4+kx] = vr ? row[kx] : 0.f;
      }
      #pragma unroll
      for (int o=0;o<10;o++){
        const float* wr = w7 + o*1024 + ci*16;
        #pragma unroll
        for (int k=0;k<16;k++) acc[o] += wr[k]*xt[k];
      }
    }
    #pragma unroll
    for (int o=0;o<10;o++) vals[bl][o][pos] = acc[o];
  }
  __syncthreads();
  if (t < 80){
    int b2 = t/10, o = t - b2*10;
    float m = vals[b2][o][0];
    #pragma unroll
    for (int p=1;p<25;p++) m = fmaxf(m, vals[b2][o][p]);
    out[(b0+b2)*10 + o] = m + bias[o];
  }
  if (blockIdx.x == 0 && t == 255) out[20480] = nmsa[0] * (1.f/12845056.f);
}

extern "C" void kernel_launch(void* const* d_in, const int* in_sizes, int n_in,
                              void* d_out, int out_size, void* d_ws, size_t ws_size,
                              hipStream_t stream){
  const float* x  = (const float*)d_in[0];
  const float* w1 = (const float*)d_in[1];
  const float* w2 = (const float*)d_in[2];
  const float* w3 = (const float*)d_in[3];
  const float* w4 = (const float*)d_in[4];
  const float* w5 = (const float*)d_in[5];
  const float* w6 = (const float*)d_in[6];
  const float* w7 = (const float*)d_in[7];
  const float* g1 = (const float*)d_in[8];
  const float* b1 = (const float*)d_in[9];
  const float* g2 = (const float*)d_in[10];
  const float* b2 = (const float*)d_in[11];
  const float* g3 = (const float*)d_in[12];
  const float* b3 = (const float*)d_in[13];
  const float* g4 = (const float*)d_in[14];
  const float* b4 = (const float*)d_in[15];
  const float* g5 = (const float*)d_in[16];
  const float* b5 = (const float*)d_in[17];
  const float* g6 = (const float*)d_in[18];
  const float* b6 = (const float*)d_in[19];
  const float* b7 = (const float*)d_in[20];
  float* out = (float*)d_out;
  float* W = (float*)d_ws;

  // arena (floats), all disjoint:
  float* xpad = W;                     //  2,097,152  (2048*1024)
  float* p2p  = W + 2097152;           //  8,388,608  (2048*16*256)
  float* y3p  = W + 10485760;          // 16,777,216  (2048*32*256)
  float* p4   = W + 27262976;          //  3,407,872  (2048*32*52)
  float* y5   = W + 30670848;          //  6,815,744  (2048*64*52)
  float* y6   = W + 37486592;          //  6,422,528  (2048*64*49)
  float* p6   = W + 43909120;          //  2,097,152  (2048*64*16)
  float* wT5  = W + 46006272;          //  18,432
  float* wT6  = W + 46024704;          //  36,864
  float* st   = W + 46061568;          //  2,048

  float* cf = st + 768;
  float* nmsa = st + 1536;

  k_zero<<<8,256,0,stream>>>(st);
  k_xpad<<<8192,256,0,stream>>>(x, xpad);
  k_wt<<<216,256,0,stream>>>(w5, w6, wT5, wT6);

  k_stats1<<<512,256,0,stream>>>(x, w1, st + 0*128);
  k_fin<<<1,64,0,stream>>>(st + 0*128, g1, b1, cf + 0*128, 16, 1, 1.f/1605632.f);

  k_conv2<<<1568,256,0,stream>>>(xpad, w1, w2, cf + 0*128, p2p, st + 1*128);
  k_fin<<<1,64,0,stream>>>(st + 1*128, g2, b2, cf + 1*128, 16, 1, 1.f/1605632.f);

  k_conv3<<<784,256,0,stream>>>(p2p, w3, cf + 1*128, y3p, st + 2*128);
  k_fin<<<1,64,0,stream>>>(st + 2*128, g3, b3, cf + 2*128, 32, 3, 1.f/401408.f);
  k_nms<<<6272,256,0,stream>>>(y3p, cf + 2*128, nmsa);

  k_conv4<<<784,256,0,stream>>>(y3p, w4, cf + 2*128, p4, st + 3*128);
  k_fin<<<1,64,0,stream>>>(st + 3*128, g4, b4, cf + 3*128, 32, 31, 1.f/401408.f);

  k_conv5<<<512,256,0,stream>>>(p4, wT5, cf + 3*128, y5, st + 4*128);
  k_fin<<<1,64,0,stream>>>(st + 4*128, g5, b5, cf + 4*128, 64, 63, 1.f/100352.f);

  k_conv6<<<512,256,0,stream>>>(y5, wT6, cf + 4*128, y6, st + 5*128);
  k_fin<<<1,64,0,stream>>>(st + 5*128, g6, b6, cf + 5*128, 64, 63, 1.f/100352.f);
  k_pool6<<<8192,256,0,stream>>>(y6, cf + 5*128, p6);

  k_conv7<<<256,256,0,stream>>>(p6, w7, b7, nmsa, out);
}

// Round 6
// 944.481 us; speedup vs baseline: 2.3394x; 1.1294x over previous
//
#include <hip/hip_runtime.h>

static constexpr int NB = 2048;
static constexpr float SENT = -1e30f;

// rotated-3x3 tap permutation: weight tap k of rotation r lands at patch position DST[r][k]
static constexpr int DST[8][9] = {
  {8,7,6,5,4,3,2,1,0},
  {5,8,7,2,4,6,1,0,3},
  {2,5,8,1,4,7,0,3,6},
  {1,2,5,0,4,8,3,6,7},
  {0,1,2,3,4,5,6,7,8},
  {3,0,1,6,4,2,7,8,5},
  {6,3,0,7,4,1,8,5,2},
  {7,6,3,8,4,0,5,2,1},
};

__device__ __forceinline__ unsigned short f2bf(float f){
  unsigned int u = __float_as_uint(f);
  u += 0x7fffu + ((u>>16)&1u);          // RNE
  return (unsigned short)(u>>16);
}

// border cell index (16x16 plane) for border id t<60
__device__ __forceinline__ int border_cell(int t){
  if (t<16) return t;
  if (t<32) return 240 + (t-16);
  if (t<46) return (t-31)*16;
  return (t-45)*16 + 15;
}
// border cell (row,col) for 30x30-used region of a 30x32 plane, id t<116
__device__ __forceinline__ int border_cell30(int t){
  if (t<30) return t;                    // row 0
  if (t<60) return 29*32 + (t-30);       // row 29
  if (t<88) return (t-59)*32;            // col 0, rows 1..28
  return (t-87)*32 + 29;                 // col 29, rows 1..28
}

// ---------------- zero stats region ----------------
__global__ __launch_bounds__(256) void k_zero(float* st){
  int i = blockIdx.x*256 + threadIdx.x;
  if (i < 2048) st[i] = 0.f;
}

// ---------------- transpose w5,w6 to [ci*9+k][oc] ----------------
__global__ __launch_bounds__(256) void k_wt(const float* __restrict__ w5, const float* __restrict__ w6,
                                            float* __restrict__ wT5, float* __restrict__ wT6){
  int i = blockIdx.x*256 + threadIdx.x;
  if (i < 32*9*64){
    int ck = i>>6, oc = i&63; int ci = ck/9, k = ck - ci*9;
    wT5[ck*64+oc] = w5[(oc*32+ci)*9 + k];
  } else if (i < 32*9*64 + 64*9*64){
    int j = i - 32*9*64;
    int ck = j>>6, oc = j&63; int ci = ck/9, k = ck - ci*9;
    wT6[ck*64+oc] = w6[(oc*64+ci)*9 + k];
  }
}

// ---------------- conv1: 1->16 rotated, bf16 padded planes (30x32, sentinel border) + fused stats ----------------
__global__ __launch_bounds__(256) void k_conv1(const float* __restrict__ x,
                                               const float* __restrict__ w1,
                                               unsigned short* __restrict__ y1p,
                                               float* __restrict__ st){
  __shared__ float wp[192];
  __shared__ float red[4][32];
  for (int i=threadIdx.x; i<144; i+=256){
    int rot = i/18, rem = i-rot*18, u = rem/9, k = rem-u*9;
    wp[(rot*2+u)*12 + DST[rot][k]] = w1[u*9+k];
  }
  __syncthreads();
  int idx = blockIdx.x*256 + threadIdx.x;      // 2048*784 exact (6272 blocks)
  int b = idx/784, pix = idx-b*784;
  int py = pix/28, px = pix-py*28;
  const float* xb = x + (size_t)b*784;
  float tap[9];
  #pragma unroll
  for (int d=0; d<9; d++){
    int dy = d/3-1, dx = d%3-1;
    int yy = py+dy, xx = px+dx;
    tap[d] = (yy>=0 && yy<28 && xx>=0 && xx<28) ? xb[yy*28+xx] : 0.f;
  }
  float ych[16];
  #pragma unroll
  for (int ci=0; ci<16; ci++){
    float y = 0.f;
    #pragma unroll
    for (int d=0; d<9; d++) y += wp[ci*12+d]*tap[d];
    ych[ci] = y;
  }
  unsigned short* yb = y1p + (size_t)b*15360 + (py+1)*32 + (px+1);
  #pragma unroll
  for (int ci=0; ci<16; ci++) yb[ci*960] = f2bf(ych[ci]);
  if (pix < 116){
    int bc = border_cell30(pix);
    unsigned short sb = f2bf(SENT);
    unsigned short* bb = y1p + (size_t)b*15360 + bc;
    #pragma unroll
    for (int ci=0; ci<16; ci++) bb[ci*960] = sb;
  }
  int wid = threadIdx.x>>6;
  #pragma unroll
  for (int o=0;o<16;o++){
    float a = ych[o], b2 = ych[o]*ych[o];
    #pragma unroll
    for (int off=32; off; off>>=1){ a += __shfl_down(a,off); b2 += __shfl_down(b2,off); }
    if ((threadIdx.x&63)==0){ red[wid][o] = a; red[wid][16+o] = b2; }
  }
  __syncthreads();
  if (threadIdx.x < 32){
    float v = red[0][threadIdx.x]+red[1][threadIdx.x]+red[2][threadIdx.x]+red[3][threadIdx.x];
    int c = threadIdx.x & 15;
    atomicAdd(&st[(threadIdx.x<16)? c : 64+c], v);
  }
}

// ---------------- BN finalize ----------------
__global__ void k_fin(const float* __restrict__ st, const float* __restrict__ g,
                      const float* __restrict__ be, float* __restrict__ coef,
                      int C, int gmask, float invN){
  int c = threadIdx.x;
  if (c >= C) return;
  float mu  = st[c]*invN;
  float var = st[64+c]*invN - mu*mu;
  float a = g[c & gmask] * rsqrtf(var + 1e-5f);
  coef[c]    = a;
  coef[64+c] = be[c & gmask] - mu*a;
}

// ---------------- conv2: bf16 y1 planes, bn1+relu on read, rot-conv 16->16, stats + raw pool -> padded p2 ----------------
__global__ __launch_bounds__(256) void k_conv2(const unsigned short* __restrict__ y1p,
                                               const float* __restrict__ w2,
                                               const float* __restrict__ coef,
                                               float* __restrict__ p2p,
                                               float* __restrict__ st){
  __shared__ float ws[384];
  __shared__ float ca[16], cb[16];
  __shared__ float red[4][32];
  for (int i=threadIdx.x; i<288; i+=256){
    int f = i/9, k = i-f*9;
    ws[f*12+k] = w2[i];
  }
  if (threadIdx.x < 16){ ca[threadIdx.x] = coef[threadIdx.x]; cb[threadIdx.x] = coef[64+threadIdx.x]; }
  __syncthreads();
  int tg = blockIdx.x*256 + threadIdx.x;    // 2048*196 (1568 blocks)
  int b = tg / 196, tile = tg - b*196;
  int ty2 = (tile/14)*2, tx2 = (tile%14)*2;
  const unsigned int* src0 = (const unsigned int*)(y1p + (size_t)b*15360);
  int cbase = (tx2>>1);
  float acc[16][4];
  #pragma unroll
  for (int o=0;o<16;o++){ acc[o][0]=0.f; acc[o][1]=0.f; acc[o][2]=0.f; acc[o][3]=0.f; }
  for (int ci=0; ci<16; ci++){
    float a = ca[ci], bo = cb[ci];
    const unsigned int* pl = src0 + ci*480;
    float t[16];
    #pragma unroll
    for (int r=0;r<4;r++){
      unsigned int w01 = pl[(ty2+r)*16 + cbase];
      unsigned int w23 = pl[(ty2+r)*16 + cbase + 1];
      float f0 = __uint_as_float(w01<<16);
      float f1 = __uint_as_float(w01 & 0xffff0000u);
      float f2 = __uint_as_float(w23<<16);
      float f3 = __uint_as_float(w23 & 0xffff0000u);
      t[r*4+0] = fmaxf(f0*a+bo, 0.f);
      t[r*4+1] = fmaxf(f1*a+bo, 0.f);
      t[r*4+2] = fmaxf(f2*a+bo, 0.f);
      t[r*4+3] = fmaxf(f3*a+bo, 0.f);
    }
    int bb = ci>>1, ui = ci&1;
    #pragma unroll
    for (int rot=0; rot<8; rot++){
      int wc = (((bb - rot) & 7)<<1) | ui;
      #pragma unroll
      for (int u=0; u<2; u++){
        const float* wr = &ws[(u*16+wc)*12];
        float4 wA = *(const float4*)wr;
        float4 wB = *(const float4*)(wr+4);
        float w8 = wr[8];
        float wv[9] = {wA.x,wA.y,wA.z,wA.w,wB.x,wB.y,wB.z,wB.w,w8};
        #pragma unroll
        for (int k=0;k<9;k++){
          int d = DST[rot][k];
          int dy = d/3, dx = d-dy*3;
          float w = wv[k];
          acc[rot*2+u][0] += w*t[dy*4+dx];
          acc[rot*2+u][1] += w*t[dy*4+dx+1];
          acc[rot*2+u][2] += w*t[(dy+1)*4+dx];
          acc[rot*2+u][3] += w*t[(dy+1)*4+dx+1];
        }
      }
    }
  }
  int cell = (tile/14 + 1)*16 + (tile%14) + 1;
  int wid = threadIdx.x>>6;
  #pragma unroll
  for (int o=0;o<16;o++){
    float m = fmaxf(fmaxf(acc[o][0],acc[o][1]), fmaxf(acc[o][2],acc[o][3]));
    p2p[((size_t)b*16+o)*256 + cell] = m;
    float s  = acc[o][0]+acc[o][1]+acc[o][2]+acc[o][3];
    float s2 = acc[o][0]*acc[o][0]+acc[o][1]*acc[o][1]+acc[o][2]*acc[o][2]+acc[o][3]*acc[o][3];
    #pragma unroll
    for (int off=32; off; off>>=1){ s += __shfl_down(s,off); s2 += __shfl_down(s2,off); }
    if ((threadIdx.x&63)==0){ red[wid][o] = s; red[wid][16+o] = s2; }
  }
  if (tile < 60){
    int bc = border_cell(tile);
    #pragma unroll
    for (int o=0;o<16;o++) p2p[((size_t)b*16+o)*256 + bc] = SENT;
  }
  __syncthreads();
  if (threadIdx.x < 32){
    float v = red[0][threadIdx.x]+red[1][threadIdx.x]+red[2][threadIdx.x]+red[3][threadIdx.x];
    int c = threadIdx.x & 15;
    atomicAdd(&st[(threadIdx.x<16)? c : 64+c], v);
  }
}

// ---------------- conv3: 16->32 rotated, bn2+relu on read (sentinel-safe), stats, padded y3 out ----------------
__global__ __launch_bounds__(256) void k_conv3(const float* __restrict__ p2p,
                                               const float* __restrict__ w3,
                                               const float* __restrict__ coef,
                                               float* __restrict__ y3p,
                                               float* __restrict__ st){
  __shared__ float ws[384];
  __shared__ float ca[16], cb[16];
  __shared__ float red[4][32];
  int uh = blockIdx.x / 392;
  int inner = blockIdx.x - uh*392;
  for (int i=threadIdx.x; i<288; i+=256){
    int f = i/9, k = i-f*9;
    ws[f*12+k] = w3[uh*288 + i];
  }
  if (threadIdx.x < 16){ ca[threadIdx.x] = coef[threadIdx.x]; cb[threadIdx.x] = coef[64+threadIdx.x]; }
  __syncthreads();
  int tg = inner*256 + threadIdx.x;
  int b = tg / 49, tile = tg - b*49;
  int ty2 = (tile/7)*2, tx2 = (tile%7)*2;
  const float* src0 = p2p + (size_t)b*4096 + ty2*16 + tx2;
  float acc[16][4];
  #pragma unroll
  for (int o=0;o<16;o++){ acc[o][0]=0.f; acc[o][1]=0.f; acc[o][2]=0.f; acc[o][3]=0.f; }
  for (int ci=0; ci<16; ci++){
    float a = ca[ci], bo = cb[ci];
    const float* s2p = src0 + ci*256;
    float t[16];
    #pragma unroll
    for (int r=0;r<4;r++){
      float2 A = *(const float2*)(s2p + r*16);
      float2 B = *(const float2*)(s2p + r*16 + 2);
      t[r*4+0] = fmaxf(A.x*a+bo, 0.f);
      t[r*4+1] = fmaxf(A.y*a+bo, 0.f);
      t[r*4+2] = fmaxf(B.x*a+bo, 0.f);
      t[r*4+3] = fmaxf(B.y*a+bo, 0.f);
    }
    int bb = ci>>1, ui = ci&1;
    #pragma unroll
    for (int rot=0; rot<8; rot++){
      int wc = (((bb - rot) & 7)<<1) | ui;
      #pragma unroll
      for (int ul=0; ul<2; ul++){
        const float* wr = &ws[(ul*16+wc)*12];
        float4 wA = *(const float4*)wr;
        float4 wB = *(const float4*)(wr+4);
        float w8 = wr[8];
        float wv[9] = {wA.x,wA.y,wA.z,wA.w,wB.x,wB.y,wB.z,wB.w,w8};
        #pragma unroll
        for (int k=0;k<9;k++){
          int d = DST[rot][k];
          int dy = d/3, dx = d-dy*3;
          float w = wv[k];
          acc[rot*2+ul][0] += w*t[dy*4+dx];
          acc[rot*2+ul][1] += w*t[dy*4+dx+1];
          acc[rot*2+ul][2] += w*t[(dy+1)*4+dx];
          acc[rot*2+ul][3] += w*t[(dy+1)*4+dx+1];
        }
      }
    }
  }
  float* ob = y3p + (size_t)b*8192 + (ty2+1)*16 + (tx2+1);
  int wid = threadIdx.x>>6;
  #pragma unroll
  for (int rot=0;rot<8;rot++){
    #pragma unroll
    for (int ul=0;ul<2;ul++){
      int j = rot*2+ul;
      float* dst = ob + (rot*4 + uh*2 + ul)*256;
      dst[0]  = acc[j][0]; dst[1]  = acc[j][1];
      dst[16] = acc[j][2]; dst[17] = acc[j][3];
      float s  = acc[j][0]+acc[j][1]+acc[j][2]+acc[j][3];
      float sq = acc[j][0]*acc[j][0]+acc[j][1]*acc[j][1]+acc[j][2]*acc[j][2]+acc[j][3]*acc[j][3];
      #pragma unroll
      for (int off=32; off; off>>=1){ s += __shfl_down(s,off); sq += __shfl_down(sq,off); }
      if ((threadIdx.x&63)==0){ red[wid][j] = s; red[wid][16+j] = sq; }
    }
  }
  for (int t2 = tile; t2 < 60; t2 += 49){
    int bc = border_cell(t2);
    #pragma unroll
    for (int rot=0;rot<8;rot++){
      #pragma unroll
      for (int ul=0;ul<2;ul++)
        y3p[((size_t)b*32 + rot*4 + uh*2 + ul)*256 + bc] = SENT;
    }
  }
  __syncthreads();
  if (threadIdx.x < 32){
    float v = red[0][threadIdx.x]+red[1][threadIdx.x]+red[2][threadIdx.x]+red[3][threadIdx.x];
    int j = threadIdx.x & 15;
    int c = (j>>1)*4 + uh*2 + (j&1);
    atomicAdd(&st[(threadIdx.x<16)? c : 64+c], v);
  }
}

// ---------------- nms (padded y3) ----------------
__global__ __launch_bounds__(256) void k_nms(const float* __restrict__ y3p,
                                             const float* __restrict__ coef,
                                             float* __restrict__ accum){
  int idx = blockIdx.x*256 + threadIdx.x;       // NB*4*196 exact
  int hw = idx % 196; int t1 = idx / 196;
  int c4 = t1 & 3;    int b = t1 >> 2;
  int py = hw/14, px = hw%14;
  const float* base = y3p + ((size_t)b*32 + c4*8)*256 + (py+1)*16 + (px+1);
  float v[8]; float vmax = -1e30f;
  #pragma unroll
  for (int r=0;r<8;r++){
    int c = c4*8 + r;
    float z = fmaxf(base[r*256]*coef[c] + coef[64+c], 0.f);
    v[r] = z;
    vmax = fmaxf(vmax, z);
  }
  float local = 0.f;
  #pragma unroll
  for (int r=0;r<8;r++) local += (v[r] != vmax) ? v[r] : 0.f;
  #pragma unroll
  for (int off=32; off; off>>=1) local += __shfl_down(local, off);
  __shared__ float sh[4];
  if ((threadIdx.x & 63) == 0) sh[threadIdx.x>>6] = local;
  __syncthreads();
  if (threadIdx.x == 0) atomicAdd(accum, sh[0]+sh[1]+sh[2]+sh[3]);
}

// ---------------- conv4: 32->32, bn3+relu on read, 16-oc halves, stats + raw pool (stride-52 planes) ----------------
__global__ __launch_bounds__(256) void k_conv4(const float* __restrict__ y3p,
                                               const float* __restrict__ w4,
                                               const float* __restrict__ coef,
                                               float* __restrict__ p4,
                                               float* __restrict__ st){
  __shared__ float ws[6144];
  __shared__ float ca[32], cb[32];
  __shared__ float red[4][32];
  int oh = blockIdx.x / 392;
  int inner = blockIdx.x - oh*392;
  for (int i=threadIdx.x; i<4608; i+=256){
    int f = i/9, k = i-f*9;
    ws[f*12+k] = w4[oh*4608 + i];
  }
  if (threadIdx.x < 32){ ca[threadIdx.x] = coef[threadIdx.x]; cb[threadIdx.x] = coef[64+threadIdx.x]; }
  __syncthreads();
  int tg = inner*256 + threadIdx.x;
  int b = tg / 49, tile = tg - b*49;
  int ty2 = (tile/7)*2, tx2 = (tile%7)*2;
  const float* src0 = y3p + (size_t)b*8192 + ty2*16 + tx2;
  float acc[16][4];
  #pragma unroll
  for (int o=0;o<16;o++){ acc[o][0]=0.f; acc[o][1]=0.f; acc[o][2]=0.f; acc[o][3]=0.f; }
  #pragma unroll 2
  for (int ci=0; ci<32; ci++){
    float a = ca[ci], bo = cb[ci];
    const float* s2p = src0 + ci*256;
    float t[16];
    #pragma unroll
    for (int r=0;r<4;r++){
      float2 A = *(const float2*)(s2p + r*16);
      float2 B = *(const float2*)(s2p + r*16 + 2);
      t[r*4+0] = fmaxf(A.x*a+bo, 0.f);
      t[r*4+1] = fmaxf(A.y*a+bo, 0.f);
      t[r*4+2] = fmaxf(B.x*a+bo, 0.f);
      t[r*4+3] = fmaxf(B.y*a+bo, 0.f);
    }
    #pragma unroll
    for (int o=0;o<16;o++){
      const float* wr = &ws[(o*32+ci)*12];
      float4 wA = *(const float4*)wr;
      float4 wB = *(const float4*)(wr+4);
      float w8 = wr[8];
      float wv[9] = {wA.x,wA.y,wA.z,wA.w,wB.x,wB.y,wB.z,wB.w,w8};
      #pragma unroll
      for (int k=0;k<9;k++){
        float w = wv[k];
        int dy = k/3, dx = k-dy*3;
        acc[o][0] += w*t[dy*4+dx];
        acc[o][1] += w*t[dy*4+dx+1];
        acc[o][2] += w*t[(dy+1)*4+dx];
        acc[o][3] += w*t[(dy+1)*4+dx+1];
      }
    }
  }
  int wid = threadIdx.x>>6;
  #pragma unroll
  for (int o=0;o<16;o++){
    float m = fmaxf(fmaxf(acc[o][0],acc[o][1]), fmaxf(acc[o][2],acc[o][3]));
    p4[((size_t)b*32 + oh*16 + o)*52 + tile] = m;
    float s  = acc[o][0]+acc[o][1]+acc[o][2]+acc[o][3];
    float sq = acc[o][0]*acc[o][0]+acc[o][1]*acc[o][1]+acc[o][2]*acc[o][2]+acc[o][3]*acc[o][3];
    #pragma unroll
    for (int off=32; off; off>>=1){ s += __shfl_down(s,off); sq += __shfl_down(sq,off); }
    if ((threadIdx.x&63)==0){ red[wid][o] = s; red[wid][16+o] = sq; }
  }
  __syncthreads();
  if (threadIdx.x < 32){
    float v = red[0][threadIdx.x]+red[1][threadIdx.x]+red[2][threadIdx.x]+red[3][threadIdx.x];
    int c = oh*16 + (threadIdx.x & 15);
    atomicAdd(&st[(threadIdx.x<16)? c : 64+c], v);
  }
}

// ---------------- conv5: 32->64, wave=batch lane=oc; bn4+relu on read; stats; stride-52 out ----------------
__global__ __launch_bounds__(256) void k_conv5(const float* __restrict__ p4,
                                               const float* __restrict__ wT5,
                                               const float* __restrict__ coef,
                                               float* __restrict__ y5,
                                               float* __restrict__ st){
  __shared__ float ca[32], cb[32];
  __shared__ float red[4][128];
  if (threadIdx.x < 32){ ca[threadIdx.x] = coef[threadIdx.x]; cb[threadIdx.x] = coef[64+threadIdx.x]; }
  __syncthreads();
  int wid = threadIdx.x>>6;
  int lane = threadIdx.x&63;
  int b = blockIdx.x*4 + wid;
  const float* src = p4 + (size_t)b*32*52;
  float acc[49];
  #pragma unroll
  for (int p=0;p<49;p++) acc[p] = 0.f;
  for (int ci=0; ci<32; ci++){
    float a = ca[ci], bo = cb[ci];
    const float* pl = src + ci*52;
    float raw[52] __attribute__((aligned(16)));
    #pragma unroll
    for (int j=0;j<12;j++) *(float4*)&raw[j*4] = *(const float4*)(pl + j*4);
    raw[48] = pl[48];
    float wv[9];
    #pragma unroll
    for (int k=0;k<9;k++) wv[k] = wT5[(ci*9+k)*64 + lane];
    #pragma unroll
    for (int p=0;p<49;p++){
      float v = fmaxf(raw[p]*a + bo, 0.f);
      int iy = p/7, ix = p%7;
      #pragma unroll
      for (int k=0;k<9;k++){
        int dy = k/3, dx = k-dy*3;
        int oy = iy-dy+1, ox = ix-dx+1;
        if (oy>=0 && oy<7 && ox>=0 && ox<7) acc[oy*7+ox] += wv[k]*v;
      }
    }
  }
  float* dst = y5 + ((size_t)b*64 + lane)*52;
  float s=0.f, sq=0.f;
  #pragma unroll
  for (int p=0;p<49;p++){ dst[p] = acc[p]; s += acc[p]; sq += acc[p]*acc[p]; }
  red[wid][lane] = s; red[wid][64+lane] = sq;
  __syncthreads();
  if (threadIdx.x < 128){
    float v = red[0][threadIdx.x]+red[1][threadIdx.x]+red[2][threadIdx.x]+red[3][threadIdx.x];
    int c = threadIdx.x & 63;
    atomicAdd(&st[(threadIdx.x<64)? c : 64+c], v);
  }
}

// ---------------- conv6: 64->64, wave=batch lane=oc; bn5+relu on read; stats; 49-stride out ----------------
__global__ __launch_bounds__(256) void k_conv6(const float* __restrict__ y5,
                                               const float* __restrict__ wT6,
                                               const float* __restrict__ coef,
                                               float* __restrict__ y6,
                                               float* __restrict__ st){
  __shared__ float ca[64], cb[64];
  __shared__ float red[4][128];
  if (threadIdx.x < 64){ ca[threadIdx.x] = coef[threadIdx.x]; cb[threadIdx.x] = coef[64+threadIdx.x]; }
  __syncthreads();
  int wid = threadIdx.x>>6;
  int lane = threadIdx.x&63;
  int b = blockIdx.x*4 + wid;
  const float* src = y5 + (size_t)b*64*52;
  float acc[49];
  #pragma unroll
  for (int p=0;p<49;p++) acc[p] = 0.f;
  for (int ci=0; ci<64; ci++){
    float a = ca[ci], bo = cb[ci];
    const float* pl = src + ci*52;
    float raw[52] __attribute__((aligned(16)));
    #pragma unroll
    for (int j=0;j<12;j++) *(float4*)&raw[j*4] = *(const float4*)(pl + j*4);
    raw[48] = pl[48];
    float wv[9];
    #pragma unroll
    for (int k=0;k<9;k++) wv[k] = wT6[(ci*9+k)*64 + lane];
    #pragma unroll
    for (int p=0;p<49;p++){
      float v = fmaxf(raw[p]*a + bo, 0.f);
      int iy = p/7, ix = p%7;
      #pragma unroll
      for (int k=0;k<9;k++){
        int dy = k/3, dx = k-dy*3;
        int oy = iy-dy+1, ox = ix-dx+1;
        if (oy>=0 && oy<7 && ox>=0 && ox<7) acc[oy*7+ox] += wv[k]*v;
      }
    }
  }
  float* dst = y6 + ((size_t)b*64 + lane)*49;
  float s=0.f, sq=0.f;
  #pragma unroll
  for (int p=0;p<49;p++){ dst[p] = acc[p]; s += acc[p]; sq += acc[p]*acc[p]; }
  red[wid][lane] = s; red[wid][64+lane] = sq;
  __syncthreads();
  if (threadIdx.x < 128){
    float v = red[0][threadIdx.x]+red[1][threadIdx.x]+red[2][threadIdx.x]+red[3][threadIdx.x];
    int c = threadIdx.x & 63;
    atomicAdd(&st[(threadIdx.x<64)? c : 64+c], v);
  }
}

// ---------------- bn6+relu + 2x2 pool pad 1 (7 -> 4) ----------------
__global__ __launch_bounds__(256) void k_pool6(const float* __restrict__ y,
                                               const float* __restrict__ coef,
                                               float* __restrict__ p){
  int idx = blockIdx.x*256 + threadIdx.x;       // NB*64*16 exact
  int xo = idx & 3; int t1 = idx >> 2;
  int yo = t1 & 3;  int t2 = t1 >> 2;
  int c = t2 & 63;  int b = t2 >> 6;
  float a = coef[c], bo = coef[64+c];
  const float* src = y + ((size_t)b*64 + c)*49;
  float m = -1e30f;
  #pragma unroll
  for (int dy=0;dy<2;dy++){
    int iy = yo*2 - 1 + dy;
    if (iy < 0 || iy >= 7) continue;
    #pragma unroll
    for (int dx=0;dx<2;dx++){
      int ix = xo*2 - 1 + dx;
      if (ix < 0 || ix >= 7) continue;
      m = fmaxf(m, src[iy*7+ix]*a + bo);
    }
  }
  p[idx] = fmaxf(m, 0.f);
}

// ---------------- conv7 ----------------
__global__ __launch_bounds__(256) void k_conv7(const float* __restrict__ p6,
                                               const float* __restrict__ w7,
                                               const float* __restrict__ bias,
                                               const float* __restrict__ nmsa,
                                               float* __restrict__ out){
  __shared__ float xs[8*2056];
  __shared__ float vals[8][10][25];
  int b0 = blockIdx.x*8;                     // grid 256
  for (int i=threadIdx.x; i<8*2056; i+=256) xs[i] = 0.f;
  __syncthreads();
  for (int i=threadIdx.x; i<8192; i+=256){
    int bl = i>>10, rem = i&1023;
    int ci = rem>>4, r = (rem>>2)&3, c = rem&3;
    xs[bl*2056 + ci*32 + r*8 + c + 2] = p6[(size_t)(b0+bl)*1024 + rem];
  }
  __syncthreads();
  int t = threadIdx.x;
  int bl = t/25, pos = t - bl*25;
  if (bl < 8){
    int py = pos/5, px = pos - py*5;
    float acc[10];
    #pragma unroll
    for (int o=0;o<10;o++) acc[o] = 0.f;
    for (int ci=0; ci<64; ci++){
      float xt[16];
      #pragma unroll
      for (int ky=0; ky<4; ky++){
        int r = py + ky - 2;
        bool vr = (r>=0 && r<4);
        int rr = vr ? r : 0;
        const float* row = &xs[bl*2056 + ci*32 + rr*8 + px];
        #pragma unroll
        for (int kx=0;kx<4;kx++) xt[ky*4+kx] = vr ? row[kx] : 0.f;
      }
      #pragma unroll
      for (int o=0;o<10;o++){
        const float* wr = w7 + o*1024 + ci*16;
        #pragma unroll
        for (int k=0;k<16;k++) acc[o] += wr[k]*xt[k];
      }
    }
    #pragma unroll
    for (int o=0;o<10;o++) vals[bl][o][pos] = acc[o];
  }
  __syncthreads();
  if (t < 80){
    int b2 = t/10, o = t - b2*10;
    float m = vals[b2][o][0];
    #pragma unroll
    for (int p=1;p<25;p++) m = fmaxf(m, vals[b2][o][p]);
    out[(b0+b2)*10 + o] = m + bias[o];
  }
  if (blockIdx.x == 0 && t == 255) out[20480] = nmsa[0] * (1.f/12845056.f);
}

extern "C" void kernel_launch(void* const* d_in, const int* in_sizes, int n_in,
                              void* d_out, int out_size, void* d_ws, size_t ws_size,
                              hipStream_t stream){
  const float* x  = (const float*)d_in[0];
  const float* w1 = (const float*)d_in[1];
  const float* w2 = (const float*)d_in[2];
  const float* w3 = (const float*)d_in[3];
  const float* w4 = (const float*)d_in[4];
  const float* w5 = (const float*)d_in[5];
  const float* w6 = (const float*)d_in[6];
  const float* w7 = (const float*)d_in[7];
  const float* g1 = (const float*)d_in[8];
  const float* b1 = (const float*)d_in[9];
  const float* g2 = (const float*)d_in[10];
  const float* b2 = (const float*)d_in[11];
  const float* g3 = (const float*)d_in[12];
  const float* b3 = (const float*)d_in[13];
  const float* g4 = (const float*)d_in[14];
  const float* b4 = (const float*)d_in[15];
  const float* g5 = (const float*)d_in[16];
  const float* b5 = (const float*)d_in[17];
  const float* g6 = (const float*)d_in[18];
  const float* b6 = (const float*)d_in[19];
  const float* b7 = (const float*)d_in[20];
  float* out = (float*)d_out;
  float* W = (float*)d_ws;

  // arena (float units). y1p (bf16) dead after conv2 -> overlaid by p4/y5/y6/p6.
  unsigned short* y1p = (unsigned short*)W;   // 2048*16*960 bf16 = 15,728,640 floats
  float* p2p  = W + 15728640;          //  8,388,608  (2048*16*256)
  float* y3p  = W + 24117248;          // 16,777,216  (2048*32*256)
  float* p4   = W + 0;                 //  3,407,872  (overlay y1p)
  float* y5   = W + 3407872;           //  6,815,744  (overlay y1p)
  float* y6   = W + 10223616;          //  6,422,528  (overlay y1p tail + p2p head; both dead)
  float* p6   = W + 16646144;          //  2,097,152  (overlay dead p2p)
  float* wT5  = W + 40894464;          //  18,432
  float* wT6  = W + 40912896;          //  36,864
  float* st   = W + 40949760;          //  2,048

  float* cf = st + 768;
  float* nmsa = st + 1536;

  k_zero<<<8,256,0,stream>>>(st);
  k_wt<<<216,256,0,stream>>>(w5, w6, wT5, wT6);

  k_conv1<<<6272,256,0,stream>>>(x, w1, y1p, st + 0*128);
  k_fin<<<1,64,0,stream>>>(st + 0*128, g1, b1, cf + 0*128, 16, 1, 1.f/1605632.f);

  k_conv2<<<1568,256,0,stream>>>(y1p, w2, cf + 0*128, p2p, st + 1*128);
  k_fin<<<1,64,0,stream>>>(st + 1*128, g2, b2, cf + 1*128, 16, 1, 1.f/1605632.f);

  k_conv3<<<784,256,0,stream>>>(p2p, w3, cf + 1*128, y3p, st + 2*128);
  k_fin<<<1,64,0,stream>>>(st + 2*128, g3, b3, cf + 2*128, 32, 3, 1.f/401408.f);
  k_nms<<<6272,256,0,stream>>>(y3p, cf + 2*128, nmsa);

  k_conv4<<<784,256,0,stream>>>(y3p, w4, cf + 2*128, p4, st + 3*128);
  k_fin<<<1,64,0,stream>>>(st + 3*128, g4, b4, cf + 3*128, 32, 31, 1.f/401408.f);

  k_conv5<<<512,256,0,stream>>>(p4, wT5, cf + 3*128, y5, st + 4*128);
  k_fin<<<1,64,0,stream>>>(st + 4*128, g5, b5, cf + 4*128, 64, 63, 1.f/100352.f);

  k_conv6<<<512,256,0,stream>>>(y5, wT6, cf + 4*128, y6, st + 5*128);
  k_fin<<<1,64,0,stream>>>(st + 5*128, g6, b6, cf + 5*128, 64, 63, 1.f/100352.f);
  k_pool6<<<8192,256,0,stream>>>(y6, cf + 5*128, p6);

  k_conv7<<<256,256,0,stream>>>(p6, w7, b7, nmsa, out);
}